// Round 5
// baseline (613.909 us; speedup 1.0000x reference)
//
#include <hip/hip_runtime.h>
#include <hip/hip_bf16.h>
#include <cstdint>
#include <cstddef>

// Problem constants
#define NMEM 16
#define DDIM 512
#define BATCH 4
#define LSEQ 4096
#define ROWS 16384      // BATCH*LSEQ
#define NCAND 32        // fp8-noise safety: rank-8..32 gap ~4.5+ sigma
#define KTOP 8
#define QPAD 20

typedef __attribute__((ext_vector_type(4))) float f32x4;
typedef __attribute__((ext_vector_type(16))) float f32x16;
typedef __attribute__((ext_vector_type(8))) int int8v;

__device__ inline void gld16(const void* gptr, void* lptr) {
    __builtin_amdgcn_global_load_lds(
        (const __attribute__((address_space(1))) unsigned int*)gptr,
        (__attribute__((address_space(3))) unsigned int*)lptr,
        16, 0, 0);
}

// Polynomial tanh: t(27+t^2)/(27+9t^2), t = clamp(x,-3,3). Max abs err ~0.02,
// only used for approximate candidate logits (exact path uses tanhf).
__device__ inline float fast_tanh(float x) {
    float t = __builtin_amdgcn_fmed3f(x, -3.f, 3.f);
    float t2 = t * t;
    return t * (27.f + t2) * __builtin_amdgcn_rcpf(27.f + 9.f * t2);
}

// 32-byte MFMA fragment loaded straight from global (Q8 rows, L2/L3-resident).
__device__ inline int8v ldg_frag(const unsigned char* p) {
    int4 x = *(const int4*)p;
    int4 y = *(const int4*)(p + 16);
    int8v v;
    v[0] = x.x; v[1] = x.y; v[2] = x.z; v[3] = x.w;
    v[4] = y.x; v[5] = y.y; v[6] = y.z; v[7] = y.w;
    return v;
}

// W fragment from an 8 KB half-tile [128 rows][64 B]:
// global granule j of row r lives at slot j ^ ((r>>1)&3)  (bank-spread key)
__device__ inline int8v load_frag_half(const unsigned char* Ts, int row, int kh) {
    int key = (row >> 1) & 3;
    const int4* p0 = (const int4*)(Ts + row * 64 + ((((kh << 1) | 0) ^ key) << 4));
    const int4* p1 = (const int4*)(Ts + row * 64 + ((((kh << 1) | 1) ^ key) << 4));
    int4 x = *p0, y = *p1;
    int8v v;
    v[0] = x.x; v[1] = x.y; v[2] = x.z; v[3] = x.w;
    v[4] = y.x; v[5] = y.y; v[6] = y.z; v[7] = y.w;
    return v;
}

// coalesced stage of one [128 rows][64 B] W half-tile into an 8 KB LDS buffer.
// Wbase = &W[row0][byte-col0] of the half (rows are DDIM bytes apart).
// LDS dest is linear (gld16 requirement); source pre-swizzled to match reader.
__device__ inline void stage_half(const unsigned char* Wbase, unsigned char* dst,
                                  int tid) {
    #pragma unroll
    for (int i = 0; i < 2; ++i) {
        int c = i * 256 + tid;          // 0..511 chunk index
        int row = c >> 2, s = c & 3;
        gld16(Wbase + (size_t)row * DDIM + ((s ^ ((row >> 1) & 3)) << 4),
              dst + c * 16);
    }
}

// ---------- fused prep: Q->fp8, W1/W2 transpose->fp8 ----------
// grid: 2048 (Q) + 1024 (W1) + 1024 (W2) = 4096
__global__ __launch_bounds__(256)
void prep_kernel(const float* __restrict__ query,
                 const float* __restrict__ W1, const float* __restrict__ W2,
                 unsigned char* __restrict__ Q8,
                 unsigned char* __restrict__ W1T8, unsigned char* __restrict__ W2T8) {
    int blk = blockIdx.x, t = threadIdx.x;
    if (blk < 2048) {                       // Q convert: 16 els/thread
        size_t base = ((size_t)blk * 256 + t) * 16;
        const float4* in = (const float4*)(query + base);
        int4 o; int* op = (int*)&o;
        #pragma unroll
        for (int q = 0; q < 4; ++q) {
            float4 v = in[q];
            int lo = __builtin_amdgcn_cvt_pk_fp8_f32(v.x, v.y, 0, false);
            op[q] = __builtin_amdgcn_cvt_pk_fp8_f32(v.z, v.w, lo, true);
        }
        *(int4*)(Q8 + base) = o;
    } else {                                // W transpose+convert, 64x64 tiles
        __shared__ float tile[64][69];
        int bid = blk - 2048;               // 0..2047: 1024 per matrix
        const float* Win = W1; unsigned char* Wout = W1T8;
        if (bid >= 1024) { bid -= 1024; Win = W2; Wout = W2T8; }
        int n = bid >> 6, t64 = bid & 63;   // n in [0,16), 64 tiles of 64x64
        int dt = (t64 >> 3) << 6, jt = (t64 & 7) << 6;
        const float* inN = Win + (size_t)n * DDIM * DDIM;
        unsigned char* outN = Wout + (size_t)n * DDIM * DDIM;
        int rr = t >> 4, cc = (t & 15) * 4;
        #pragma unroll
        for (int pass = 0; pass < 4; ++pass) {
            int row = rr + pass * 16;
            float4 v = *(const float4*)(inN + (size_t)(dt + row) * DDIM + jt + cc);
            tile[row][cc] = v.x; tile[row][cc + 1] = v.y;
            tile[row][cc + 2] = v.z; tile[row][cc + 3] = v.w;
        }
        __syncthreads();
        #pragma unroll
        for (int pass = 0; pass < 4; ++pass) {
            int jl = rr + pass * 16;
            float f0 = tile[cc][jl], f1 = tile[cc + 1][jl];
            float f2 = tile[cc + 2][jl], f3 = tile[cc + 3][jl];
            int lo = __builtin_amdgcn_cvt_pk_fp8_f32(f0, f1, 0, false);
            int dw = __builtin_amdgcn_cvt_pk_fp8_f32(f2, f3, lo, true);
            *(int*)(outN + (size_t)(jt + jl) * DDIM + dt + cc) = dw;
        }
    }
}

// ---------- fused MLP (v8): depth-1 pipelined staging, rotated Q-frags ----
// grid 2048 = 128 m-tiles x 16 slots. Block 256 = 4 waves (rh, ch).
// 64 phases (A:32, B:32), one per (n0,kt,ks) half-tile. Per phase:
// issue stage of p+1 into Bs[(p+1)&1] + prefetch next Q-frags (A only),
// then ds_read + 4 MFMAs on Bs[p&1], then ONE __syncthreads() whose vmcnt
// drain covers loads that aged a full compute section.
// Q-frags: depth-1 register rotation avc/avn (32 VGPRs) — NOT the v7 full
// hoist (128 VGPRs -> scratch spills -> 580 MB/dispatch HBM, the v7 bug).
// LDS = hbuf 64 KB + Bs 2x8 KB = 80 KB -> 2 blocks/CU.
__global__ __launch_bounds__(256, 2)
void fused_mlp_kernel(const unsigned char* __restrict__ Q8,
                      const unsigned char* __restrict__ W1T8,
                      const unsigned char* __restrict__ W2T8,
                      const float* __restrict__ b1, const float* __restrict__ b2,
                      const float* __restrict__ Wg,
                      float* __restrict__ logits)
{
    __shared__ unsigned char hbuf[128 * 512];  // 64 KB fp8 h, chunk^(row&7) swizzle
    __shared__ unsigned char Bs[2][8192];      // double-buffered W half-tiles
    const int id = blockIdx.x;
    const int n = id & 15;
    const int m0 = (id >> 4) * 128;
    const int tid = threadIdx.x, lane = tid & 63;
    const int w = tid >> 6;
    const int rh = w >> 1, ch = w & 1;
    const int l31 = lane & 31, kh = lane >> 5;
    const unsigned char* W1n = W1T8 + (size_t)n * DDIM * DDIM;
    const unsigned char* W2n = W2T8 + (size_t)n * DDIM * DDIM;
    const float slope = 0.01f + 0.0125f * n;
    const unsigned char* Aq0 = Q8 + (size_t)(m0 + rh * 64 + l31) * DDIM + kh * 32;

    // prologue: stage phase 0 + load its Q-frags; one drain
    int8v avc[2];
    #pragma unroll
    for (int rt = 0; rt < 2; ++rt)
        avc[rt] = ldg_frag(Aq0 + (size_t)rt * 32 * DDIM);
    stage_half(W1n, Bs[0], tid);
    __syncthreads();

    // ---- Phase A: h^T = (Q W1)^T via swapped operands; lane holds Q-row
    //      r = rh*64+rt*32+l31, cols j = n0*128+ch*64+fc*32+(reg&3)+8(reg>>2)+4kh
    #pragma unroll 1
    for (int n0 = 0; n0 < 4; ++n0) {
        f32x16 acc[2][2] = {};   // [rt][fc]
        #pragma unroll
        for (int kt = 0; kt < 4; ++kt) {
            #pragma unroll
            for (int ks = 0; ks < 2; ++ks) {
                int q  = n0 * 8 + kt * 2 + ks;
                int qn = q + 1;                    // next phase (32 => W2 half 0)
                const unsigned char* nsrc =
                    (qn == 32) ? W2n
                               : W1n + (size_t)((qn >> 3) * 128) * DDIM
                                     + ((qn >> 1) & 3) * 128 + (qn & 1) * 64;
                stage_half(nsrc, Bs[qn & 1], tid);
                // depth-1 Q-frag prefetch: av pattern repeats mod 8 phases
                int qa = qn & 7;
                int8v avn[2];
                #pragma unroll
                for (int rt = 0; rt < 2; ++rt)
                    avn[rt] = ldg_frag(Aq0 + (size_t)rt * 32 * DDIM
                                       + ((qa >> 1) & 3) * 128 + (qa & 1) * 64);
                const unsigned char* Ts = Bs[q & 1];
                #pragma unroll
                for (int fc = 0; fc < 2; ++fc) {
                    int8v wfr = load_frag_half(Ts, ch * 64 + fc * 32 + l31, kh);
                    #pragma unroll
                    for (int rt = 0; rt < 2; ++rt)
                        acc[rt][fc] = __builtin_amdgcn_mfma_scale_f32_32x32x64_f8f6f4(
                            wfr, avc[rt], acc[rt][fc], 0, 0, 0,
                            0x7F7F7F7F, 0, 0x7F7F7F7F);
                }
                avc[0] = avn[0]; avc[1] = avn[1];
                __syncthreads();   // drains this phase's stage (aged one phase)
            }
        }
        // epilogue: bias + leaky + fp8-pack, one ds_write_b32 per reg-quad
        #pragma unroll
        for (int fc = 0; fc < 2; ++fc) {
            #pragma unroll
            for (int rt = 0; rt < 2; ++rt) {
                int r = rh * 64 + rt * 32 + l31;
                #pragma unroll
                for (int q = 0; q < 4; ++q) {
                    int jb = n0 * 128 + ch * 64 + fc * 32 + 8 * q + 4 * kh;
                    float4 bias = *(const float4*)(b1 + n * DDIM + jb);
                    float v0 = acc[rt][fc][4 * q + 0] + bias.x;
                    float v1 = acc[rt][fc][4 * q + 1] + bias.y;
                    float v2 = acc[rt][fc][4 * q + 2] + bias.z;
                    float v3 = acc[rt][fc][4 * q + 3] + bias.w;
                    v0 = v0 >= 0.f ? v0 : v0 * slope;
                    v1 = v1 >= 0.f ? v1 : v1 * slope;
                    v2 = v2 >= 0.f ? v2 : v2 * slope;
                    v3 = v3 >= 0.f ? v3 : v3 * slope;
                    int lo = __builtin_amdgcn_cvt_pk_fp8_f32(v0, v1, 0, false);
                    int dw = __builtin_amdgcn_cvt_pk_fp8_f32(v2, v3, lo, true);
                    *(int*)(hbuf + r * 512 + ((((jb >> 4) ^ (r & 7)) << 4) | (jb & 15))) = dw;
                }
            }
        }
    }

    __syncthreads();   // hbuf fully written before Phase B

    // ---- Phase B: rowsum = sum_j tanh(h W2 + b2)[row][j] * Wg[j] ----
    float rowacc[2][16] = {};
    #pragma unroll 1
    for (int n0 = 0; n0 < 4; ++n0) {
        f32x16 acc[2][2] = {};
        #pragma unroll
        for (int kt = 0; kt < 4; ++kt) {
            #pragma unroll
            for (int ks = 0; ks < 2; ++ks) {
                int q  = n0 * 8 + kt * 2 + ks;   // local phase 0..31
                int qn = q + 1;
                if (qn < 32)
                    stage_half(W2n + (size_t)((qn >> 3) * 128) * DDIM
                                   + ((qn >> 1) & 3) * 128 + (qn & 1) * 64,
                               Bs[qn & 1], tid);
                int8v hv[2];
                #pragma unroll
                for (int rt = 0; rt < 2; ++rt) {
                    int hrow = rh * 64 + rt * 32 + l31, hq = hrow & 7;
                    int C0 = kt * 8 + ks * 4 + 2 * kh;
                    const int4* p0 = (const int4*)(hbuf + hrow * 512 + ((C0 ^ hq) << 4));
                    const int4* p1 = (const int4*)(hbuf + hrow * 512 + (((C0 + 1) ^ hq) << 4));
                    int4 x = *p0, y = *p1;
                    hv[rt][0] = x.x; hv[rt][1] = x.y; hv[rt][2] = x.z; hv[rt][3] = x.w;
                    hv[rt][4] = y.x; hv[rt][5] = y.y; hv[rt][6] = y.z; hv[rt][7] = y.w;
                }
                const unsigned char* Ts = Bs[q & 1];
                #pragma unroll
                for (int fc = 0; fc < 2; ++fc) {
                    int8v wfr = load_frag_half(Ts, ch * 64 + fc * 32 + l31, kh);
                    #pragma unroll
                    for (int rt = 0; rt < 2; ++rt)
                        acc[rt][fc] = __builtin_amdgcn_mfma_scale_f32_32x32x64_f8f6f4(
                            hv[rt], wfr, acc[rt][fc], 0, 0, 0,
                            0x7F7F7F7F, 0, 0x7F7F7F7F);
                }
                __syncthreads();
            }
        }
        #pragma unroll
        for (int fc = 0; fc < 2; ++fc) {
            int j = n0 * 128 + ch * 64 + fc * 32 + l31;
            float bias = b2[n * DDIM + j];
            float wgv = Wg[n * DDIM + j];
            #pragma unroll
            for (int rt = 0; rt < 2; ++rt)
                #pragma unroll
                for (int reg = 0; reg < 16; ++reg)
                    rowacc[rt][reg] = fmaf(fast_tanh(acc[rt][fc][reg] + bias), wgv,
                                           rowacc[rt][reg]);
        }
    }
    #pragma unroll
    for (int sh = 1; sh < 32; sh <<= 1)
        #pragma unroll
        for (int rt = 0; rt < 2; ++rt)
            #pragma unroll
            for (int reg = 0; reg < 16; ++reg)
                rowacc[rt][reg] += __shfl_xor(rowacc[rt][reg], sh);
    // combine ch-halves via lsum aliased onto hbuf (all hbuf reads are done);
    // each (ch,row) entry written by exactly one lane
    __syncthreads();
    float* lsum = (float*)hbuf;   // lsum[2][128] overlays first 1 KB of hbuf
    if (l31 == 0) {
        #pragma unroll
        for (int rt = 0; rt < 2; ++rt)
            #pragma unroll
            for (int reg = 0; reg < 16; ++reg)
                lsum[ch * 128 + rh * 64 + rt * 32 + (reg & 3) + 8 * (reg >> 2) + 4 * kh]
                    = rowacc[rt][reg];
    }
    __syncthreads();
    if (tid < 128)
        logits[(size_t)n * ROWS + m0 + tid] = lsum[tid] + lsum[128 + tid];
}

// ---------- topcand: per (n,b) top-32 of 4096 ----------
__global__ __launch_bounds__(256)
void topcand_kernel(const float* __restrict__ logits, int* __restrict__ cand,
                    float* __restrict__ ex_logit) {
    __shared__ float lv[LSEQ];
    __shared__ float cv[128];
    __shared__ int   ci[128];
    int p = blockIdx.x, n = p >> 2, b = p & 3;
    int t = threadIdx.x, lane = t & 63, w = t >> 6;
    const float* L = logits + (size_t)n * ROWS + (size_t)b * LSEQ;
    for (int i = t; i < LSEQ; i += 256) lv[i] = L[i];
    __syncthreads();
    // phase 1: each wave extracts top-32 of its 1024 (register-resident)
    float mv[16];
    int base = w * 1024;
    #pragma unroll
    for (int j = 0; j < 16; ++j) mv[j] = lv[base + j * 64 + lane];
    for (int rd = 0; rd < 32; ++rd) {
        float best = mv[0]; int bj = 0;
        #pragma unroll
        for (int j = 1; j < 16; ++j)
            if (mv[j] > best) { best = mv[j]; bj = j; }
        int bidx = base + bj * 64 + lane;
        float rv = best; int ridx = bidx;
        #pragma unroll
        for (int s = 1; s < 64; s <<= 1) {
            float ov = __shfl_xor(rv, s); int oi = __shfl_xor(ridx, s);
            if (ov > rv || (ov == rv && oi < ridx)) { rv = ov; ridx = oi; }
        }
        if (lane == 0) { cv[w * 32 + rd] = rv; ci[w * 32 + rd] = ridx; }
        if (ridx == bidx) mv[bj] = -1e30f;
    }
    __syncthreads();
    // phase 2: wave 0 merges 128 -> top-32; wave 1 zeroes ex_logit
    if (w == 0) {
        float v2[2]; int i2[2];
        #pragma unroll
        for (int k = 0; k < 2; ++k) { v2[k] = cv[k * 64 + lane]; i2[k] = ci[k * 64 + lane]; }
        for (int rd = 0; rd < 32; ++rd) {
            float best = v2[0]; int bi = i2[0]; int bk = 0;
            if (v2[1] > best || (v2[1] == best && i2[1] < bi)) { best = v2[1]; bi = i2[1]; bk = 1; }
            float rv = best; int ridx = bi;
            #pragma unroll
            for (int s = 1; s < 64; s <<= 1) {
                float ov = __shfl_xor(rv, s); int oi = __shfl_xor(ridx, s);
                if (ov > rv || (ov == rv && oi < ridx)) { rv = ov; ridx = oi; }
            }
            if (lane == 0) cand[p * NCAND + rd] = ridx;
            if (ridx == bi) v2[bk] = -1e30f;
        }
    } else if (w == 1) {
        if (lane < NCAND) ex_logit[p * NCAND + lane] = 0.f;
    }
}

// ---------- exact fp32 recompute: phase 1 (h) ----------
// grid 64p x 2ct x 8jc = 1024 blocks, 16 cands per block
__global__ __launch_bounds__(256)
void exact_h_kernel(const float* __restrict__ query,
                    const float* __restrict__ W1, const float* __restrict__ b1,
                    const int* __restrict__ cand, float* __restrict__ ex_h) {
    __shared__ float qs[DDIM][QPAD];
    __shared__ float hpart[4][16][64];
    int blk = blockIdx.x;
    int p = blk >> 4, r4 = blk & 15;
    int ct = r4 >> 3, jc = r4 & 7;
    int n = p >> 2, b = p & 3;
    int t = threadIdx.x, jj = t & 63, dg = t >> 6;
    int j = jc * 64 + jj;
    for (int c = 0; c < 16; ++c) {
        int li = cand[p * NCAND + ct * 16 + c];
        const float* qr = query + ((size_t)b * LSEQ + li) * DDIM;
        for (int d = t; d < DDIM; d += 256) qs[d][c] = qr[d];
    }
    __syncthreads();
    const float* W1n = W1 + (size_t)n * DDIM * DDIM;
    float acc[16] = {};
    for (int d = dg * 128; d < dg * 128 + 128; ++d) {
        float wvv = W1n[(size_t)d * DDIM + j];
        const float4* qv = (const float4*)&qs[d][0];
        #pragma unroll
        for (int c4 = 0; c4 < 4; ++c4) {
            float4 q4 = qv[c4];
            acc[c4 * 4 + 0] = fmaf(q4.x, wvv, acc[c4 * 4 + 0]);
            acc[c4 * 4 + 1] = fmaf(q4.y, wvv, acc[c4 * 4 + 1]);
            acc[c4 * 4 + 2] = fmaf(q4.z, wvv, acc[c4 * 4 + 2]);
            acc[c4 * 4 + 3] = fmaf(q4.w, wvv, acc[c4 * 4 + 3]);
        }
    }
    #pragma unroll
    for (int c = 0; c < 16; ++c) hpart[dg][c][jj] = acc[c];
    __syncthreads();
    const float slope = 0.01f + 0.0125f * n;
    float bias = b1[n * DDIM + j];
    for (int cc = dg; cc < 16; cc += 4) {
        float h = hpart[0][cc][jj] + hpart[1][cc][jj] + hpart[2][cc][jj]
                + hpart[3][cc][jj] + bias;
        h = h >= 0.f ? h : h * slope;
        ex_h[((size_t)p * NCAND + ct * 16 + cc) * DDIM + j] = h;
    }
}

// ---------- exact phase 2: x + exact logits ----------
__global__ __launch_bounds__(256)
void exact_x_kernel(const float* __restrict__ ex_h,
                    const float* __restrict__ W2, const float* __restrict__ b2,
                    const float* __restrict__ Wg,
                    float* __restrict__ ex_x, float* __restrict__ ex_logit) {
    __shared__ float hs[DDIM][QPAD];
    __shared__ float xpart[4][16][64];
    int blk = blockIdx.x;
    int p = blk >> 4, r4 = blk & 15;
    int ct = r4 >> 3, jc = r4 & 7;
    int n = p >> 2;
    int t = threadIdx.x, jj = t & 63, dg = t >> 6;
    int j = jc * 64 + jj;
    for (int c = 0; c < 16; ++c) {
        const float* hr = ex_h + ((size_t)p * NCAND + ct * 16 + c) * DDIM;
        for (int d = t; d < DDIM; d += 256) hs[d][c] = hr[d];
    }
    __syncthreads();
    const float* W2n = W2 + (size_t)n * DDIM * DDIM;
    float acc[16] = {};
    for (int d = dg * 128; d < dg * 128 + 128; ++d) {
        float wvv = W2n[(size_t)d * DDIM + j];
        const float4* hv = (const float4*)&hs[d][0];
        #pragma unroll
        for (int c4 = 0; c4 < 4; ++c4) {
            float4 h4 = hv[c4];
            acc[c4 * 4 + 0] = fmaf(h4.x, wvv, acc[c4 * 4 + 0]);
            acc[c4 * 4 + 1] = fmaf(h4.y, wvv, acc[c4 * 4 + 1]);
            acc[c4 * 4 + 2] = fmaf(h4.z, wvv, acc[c4 * 4 + 2]);
            acc[c4 * 4 + 3] = fmaf(h4.w, wvv, acc[c4 * 4 + 3]);
        }
    }
    #pragma unroll
    for (int c = 0; c < 16; ++c) xpart[dg][c][jj] = acc[c];
    __syncthreads();
    float bias = b2[n * DDIM + j];
    float wg = Wg[n * DDIM + j];
    for (int cc = dg; cc < 16; cc += 4) {
        float a = xpart[0][cc][jj] + xpart[1][cc][jj] + xpart[2][cc][jj]
                + xpart[3][cc][jj] + bias;
        float x = tanhf(a);
        ex_x[((size_t)p * NCAND + ct * 16 + cc) * DDIM + j] = x;
        float lp = x * wg;
        #pragma unroll
        for (int s = 1; s < 64; s <<= 1) lp += __shfl_xor(lp, s);
        if (jj == 0) atomicAdd(&ex_logit[p * NCAND + ct * 16 + cc], lp);
    }
}

// ---------- final: exact top-8 of 32, weight, combine, normalize ----------
__global__ __launch_bounds__(64)
void final_kernel(const float* __restrict__ ex_x, const float* __restrict__ ex_logit,
                  const int* __restrict__ cand, float* __restrict__ out)
{
    __shared__ float w8s[KTOP];
    __shared__ int   s8s[KTOP];
    int p = blockIdx.x, n = p >> 2, b = p & 3;
    int t = threadIdx.x;
    float myv = (t < NCAND) ? ex_logit[p * NCAND + t] : -1e30f;
    int myidx = (t < NCAND) ? cand[p * NCAND + t] : 0x7fffffff;
    float lmax = 0.f;
    for (int k = 0; k < KTOP; ++k) {
        float rv = myv; int ridx = myidx; int rl = t;
        #pragma unroll
        for (int s = 1; s < 64; s <<= 1) {
            float ov = __shfl_xor(rv, s); int oi = __shfl_xor(ridx, s); int ol = __shfl_xor(rl, s);
            if (ov > rv || (ov == rv && oi < ridx)) { rv = ov; ridx = oi; rl = ol; }
        }
        if (k == 0) lmax = rv;
        if (t == 0) { w8s[k] = __expf(rv - lmax); s8s[k] = rl; }
        if (t == rl) myv = -1e30f;
    }
    __syncthreads();
    float cvv[8];
    float sq = 0.f;
    int idx = 0;
    for (int d = t; d < DDIM; d += 64, ++idx) {
        float s = 0.f;
        #pragma unroll
        for (int k = 0; k < KTOP; ++k)
            s = fmaf(w8s[k], ex_x[((size_t)p * NCAND + s8s[k]) * DDIM + d], s);
        cvv[idx] = s;
        sq += s * s;
    }
    #pragma unroll
    for (int s = 1; s < 64; s <<= 1) sq += __shfl_xor(sq, s);
    float norm = fmaxf(sqrtf(sq), 1e-12f);
    idx = 0;
    for (int d = t; d < DDIM; d += 64, ++idx)
        out[((size_t)b * NMEM + n) * DDIM + d] = cvv[idx] / norm;
}

extern "C" void kernel_launch(void* const* d_in, const int* in_sizes, int n_in,
                              void* d_out, int out_size, void* d_ws, size_t ws_size,
                              hipStream_t stream)
{
    const float* query = (const float*)d_in[0];
    const float* W1    = (const float*)d_in[1];
    const float* b1    = (const float*)d_in[2];
    const float* W2    = (const float*)d_in[3];
    const float* b2    = (const float*)d_in[4];
    const float* Wg    = (const float*)d_in[5];
    // d_in[6] = bg cancels under softmax+normalize; d_in[7] = topk (hardcoded 8)

    char* ws = (char*)d_ws;
    const size_t MB = 1024 * 1024;
    unsigned char* Q8   = (unsigned char*)(ws);                  // 8 MB
    unsigned char* W1T8 = (unsigned char*)(ws + 8 * MB);         // 4 MB
    unsigned char* W2T8 = (unsigned char*)(ws + 12 * MB);        // 4 MB
    float* logits   = (float*)(ws + 16 * MB);                    // 1 MB
    int*   cand     = (int*)  (ws + 17 * MB);                    // 8 KB
    float* ex_logit = (float*)(ws + 17 * MB + 16384);            // 8 KB
    float* ex_h     = (float*)(ws + 20 * MB);                    // 4 MB
    float* ex_x     = (float*)(ws + 28 * MB);                    // 4 MB

    prep_kernel<<<4096, 256, 0, stream>>>(query, W1, W2, Q8, W1T8, W2T8);
    fused_mlp_kernel<<<2048, 256, 0, stream>>>(Q8, W1T8, W2T8, b1, b2, Wg, logits);
    topcand_kernel<<<64, 256, 0, stream>>>(logits, cand, ex_logit);
    exact_h_kernel<<<1024, 256, 0, stream>>>(query, W1, b1, cand, ex_h);
    exact_x_kernel<<<1024, 256, 0, stream>>>(ex_h, W2, b2, Wg, ex_x, ex_logit);
    final_kernel<<<64, 64, 0, stream>>>(ex_x, ex_logit, cand, (float*)d_out);
}

// Round 7
// 505.090 us; speedup vs baseline: 1.2154x; 1.2154x over previous
//
#include <hip/hip_runtime.h>
#include <hip/hip_bf16.h>
#include <cstdint>
#include <cstddef>

// Problem constants
#define NMEM 16
#define DDIM 512
#define BATCH 4
#define LSEQ 4096
#define ROWS 16384      // BATCH*LSEQ
#define NCAND 32        // fp8-noise safety: rank-8..32 gap ~4.5+ sigma
#define KTOP 8
#define QPAD 20

typedef __attribute__((ext_vector_type(4))) float f32x4;
typedef __attribute__((ext_vector_type(16))) float f32x16;
typedef __attribute__((ext_vector_type(8))) int int8v;

__device__ inline void gld16(const void* gptr, void* lptr) {
    __builtin_amdgcn_global_load_lds(
        (const __attribute__((address_space(1))) unsigned int*)gptr,
        (__attribute__((address_space(3))) unsigned int*)lptr,
        16, 0, 0);
}

// Polynomial tanh: t(27+t^2)/(27+9t^2), t = clamp(x,-3,3). Max abs err ~0.02,
// only used for approximate candidate logits (exact path uses tanhf).
__device__ inline float fast_tanh(float x) {
    float t = __builtin_amdgcn_fmed3f(x, -3.f, 3.f);
    float t2 = t * t;
    return t * (27.f + t2) * __builtin_amdgcn_rcpf(27.f + 9.f * t2);
}

// 32-byte MFMA fragment loaded straight from global (Q8 rows, L2/L3-resident).
__device__ inline int8v ldg_frag(const unsigned char* p) {
    int4 x = *(const int4*)p;
    int4 y = *(const int4*)(p + 16);
    int8v v;
    v[0] = x.x; v[1] = x.y; v[2] = x.z; v[3] = x.w;
    v[4] = y.x; v[5] = y.y; v[6] = y.z; v[7] = y.w;
    return v;
}

// W fragment from an 8 KB half-tile [128 rows][64 B]:
// global granule j of row r lives at slot j ^ ((r>>1)&3)  (bank-spread key)
__device__ inline int8v load_frag_half(const unsigned char* Ts, int row, int kh) {
    int key = (row >> 1) & 3;
    const int4* p0 = (const int4*)(Ts + row * 64 + ((((kh << 1) | 0) ^ key) << 4));
    const int4* p1 = (const int4*)(Ts + row * 64 + ((((kh << 1) | 1) ^ key) << 4));
    int4 x = *p0, y = *p1;
    int8v v;
    v[0] = x.x; v[1] = x.y; v[2] = x.z; v[3] = x.w;
    v[4] = y.x; v[5] = y.y; v[6] = y.z; v[7] = y.w;
    return v;
}

// coalesced stage of one [128 rows][64 B] W half-tile into an 8 KB LDS buffer.
// Wbase = &W[row0][byte-col0] of the half (rows are DDIM bytes apart).
// LDS dest is linear (gld16 requirement); source pre-swizzled to match reader.
__device__ inline void stage_half(const unsigned char* Wbase, unsigned char* dst,
                                  int tid) {
    #pragma unroll
    for (int i = 0; i < 2; ++i) {
        int c = i * 256 + tid;          // 0..511 chunk index
        int row = c >> 2, s = c & 3;
        gld16(Wbase + (size_t)row * DDIM + ((s ^ ((row >> 1) & 3)) << 4),
              dst + c * 16);
    }
}

// ---------- fused prep: Q->fp8, W1/W2 transpose->fp8 ----------
// grid: 2048 (Q) + 1024 (W1) + 1024 (W2) = 4096
__global__ __launch_bounds__(256)
void prep_kernel(const float* __restrict__ query,
                 const float* __restrict__ W1, const float* __restrict__ W2,
                 unsigned char* __restrict__ Q8,
                 unsigned char* __restrict__ W1T8, unsigned char* __restrict__ W2T8) {
    int blk = blockIdx.x, t = threadIdx.x;
    if (blk < 2048) {                       // Q convert: 16 els/thread
        size_t base = ((size_t)blk * 256 + t) * 16;
        const float4* in = (const float4*)(query + base);
        int4 o; int* op = (int*)&o;
        #pragma unroll
        for (int q = 0; q < 4; ++q) {
            float4 v = in[q];
            int lo = __builtin_amdgcn_cvt_pk_fp8_f32(v.x, v.y, 0, false);
            op[q] = __builtin_amdgcn_cvt_pk_fp8_f32(v.z, v.w, lo, true);
        }
        *(int4*)(Q8 + base) = o;
    } else {                                // W transpose+convert, 64x64 tiles
        __shared__ float tile[64][69];
        int bid = blk - 2048;               // 0..2047: 1024 per matrix
        const float* Win = W1; unsigned char* Wout = W1T8;
        if (bid >= 1024) { bid -= 1024; Win = W2; Wout = W2T8; }
        int n = bid >> 6, t64 = bid & 63;   // n in [0,16), 64 tiles of 64x64
        int dt = (t64 >> 3) << 6, jt = (t64 & 7) << 6;
        const float* inN = Win + (size_t)n * DDIM * DDIM;
        unsigned char* outN = Wout + (size_t)n * DDIM * DDIM;
        int rr = t >> 4, cc = (t & 15) * 4;
        #pragma unroll
        for (int pass = 0; pass < 4; ++pass) {
            int row = rr + pass * 16;
            float4 v = *(const float4*)(inN + (size_t)(dt + row) * DDIM + jt + cc);
            tile[row][cc] = v.x; tile[row][cc + 1] = v.y;
            tile[row][cc + 2] = v.z; tile[row][cc + 3] = v.w;
        }
        __syncthreads();
        #pragma unroll
        for (int pass = 0; pass < 4; ++pass) {
            int jl = rr + pass * 16;
            float f0 = tile[cc][jl], f1 = tile[cc + 1][jl];
            float f2 = tile[cc + 2][jl], f3 = tile[cc + 3][jl];
            int lo = __builtin_amdgcn_cvt_pk_fp8_f32(f0, f1, 0, false);
            int dw = __builtin_amdgcn_cvt_pk_fp8_f32(f2, f3, lo, true);
            *(int*)(outN + (size_t)(jt + jl) * DDIM + dt + cc) = dw;
        }
    }
}

// ---------- fused MLP (v9): depth-1 pipelined staging, ROLLED phase loop ----
// grid 2048 = 128 m-tiles x 16 slots. Block 256 = 4 waves (rh, ch).
// 64 phases (A:32, B:32), one per half-tile, runtime phase index p8 with
// #pragma unroll 1 — the v7/v8 full unroll let the scheduler hoist loads
// across 8 phases -> register blowup -> scratch spills (188/394 MB HBM).
// Per phase: issue stage of p+1 into Bs[(p+1)&1] (+ Q-frag prefetch in A),
// ds_read + 4 MFMAs on Bs[p&1], ONE __syncthreads() (vmcnt drain covers
// loads aged by the compute section). LDS = 64 + 2x8 KB = 80 KB -> 2 blk/CU.
__global__ __launch_bounds__(256, 2)
void fused_mlp_kernel(const unsigned char* __restrict__ Q8,
                      const unsigned char* __restrict__ W1T8,
                      const unsigned char* __restrict__ W2T8,
                      const float* __restrict__ b1, const float* __restrict__ b2,
                      const float* __restrict__ Wg,
                      float* __restrict__ logits)
{
    __shared__ unsigned char hbuf[128 * 512];  // 64 KB fp8 h, chunk^(row&7) swizzle
    __shared__ unsigned char Bs[2][8192];      // double-buffered W half-tiles
    const int id = blockIdx.x;
    const int n = id & 15;
    const int m0 = (id >> 4) * 128;
    const int tid = threadIdx.x, lane = tid & 63;
    const int w = tid >> 6;
    const int rh = w >> 1, ch = w & 1;
    const int l31 = lane & 31, kh = lane >> 5;
    const unsigned char* W1n = W1T8 + (size_t)n * DDIM * DDIM;
    const unsigned char* W2n = W2T8 + (size_t)n * DDIM * DDIM;
    const float slope = 0.01f + 0.0125f * n;
    const unsigned char* Aq0 = Q8 + (size_t)(m0 + rh * 64 + l31) * DDIM + kh * 32;

    // prologue: stage phase 0 + load its Q-frags; one drain
    int8v avc0 = ldg_frag(Aq0);
    int8v avc1 = ldg_frag(Aq0 + (size_t)32 * DDIM);
    stage_half(W1n, Bs[0], tid);
    __syncthreads();

    // ---- Phase A: h^T = (Q W1)^T via swapped operands; lane holds Q-row
    //      r = rh*64+rt*32+l31, cols j = n0*128+ch*64+fc*32+(reg&3)+8(reg>>2)+4kh
    #pragma unroll 1
    for (int n0 = 0; n0 < 4; ++n0) {
        f32x16 acc[2][2] = {};   // [rt][fc], static indices only
        #pragma unroll 1
        for (int p8 = 0; p8 < 8; ++p8) {
            int q  = n0 * 8 + p8;
            int qn = q + 1;                    // next phase (32 => W2 half 0)
            const unsigned char* nsrc =
                (qn == 32) ? W2n
                           : W1n + (size_t)((qn >> 3) * 128) * DDIM + (qn & 7) * 64;
            stage_half(nsrc, Bs[qn & 1], tid);
            // depth-1 Q-frag prefetch: offset repeats mod 8 phases = (qn&7)*64
            int qa = qn & 7;
            int8v avn0 = ldg_frag(Aq0 + qa * 64);
            int8v avn1 = ldg_frag(Aq0 + (size_t)32 * DDIM + qa * 64);
            const unsigned char* Ts = Bs[q & 1];
            #pragma unroll
            for (int fc = 0; fc < 2; ++fc) {
                int8v wfr = load_frag_half(Ts, ch * 64 + fc * 32 + l31, kh);
                acc[0][fc] = __builtin_amdgcn_mfma_scale_f32_32x32x64_f8f6f4(
                    wfr, avc0, acc[0][fc], 0, 0, 0, 0x7F7F7F7F, 0, 0x7F7F7F7F);
                acc[1][fc] = __builtin_amdgcn_mfma_scale_f32_32x32x64_f8f6f4(
                    wfr, avc1, acc[1][fc], 0, 0, 0, 0x7F7F7F7F, 0, 0x7F7F7F7F);
            }
            avc0 = avn0; avc1 = avn1;
            __syncthreads();   // drains this phase's stage (aged one section)
        }
        // epilogue: bias + leaky + fp8-pack, one ds_write_b32 per reg-quad
        #pragma unroll
        for (int fc = 0; fc < 2; ++fc) {
            #pragma unroll
            for (int rt = 0; rt < 2; ++rt) {
                int r = rh * 64 + rt * 32 + l31;
                #pragma unroll
                for (int q = 0; q < 4; ++q) {
                    int jb = n0 * 128 + ch * 64 + fc * 32 + 8 * q + 4 * kh;
                    float4 bias = *(const float4*)(b1 + n * DDIM + jb);
                    float v0 = acc[rt][fc][4 * q + 0] + bias.x;
                    float v1 = acc[rt][fc][4 * q + 1] + bias.y;
                    float v2 = acc[rt][fc][4 * q + 2] + bias.z;
                    float v3 = acc[rt][fc][4 * q + 3] + bias.w;
                    v0 = v0 >= 0.f ? v0 : v0 * slope;
                    v1 = v1 >= 0.f ? v1 : v1 * slope;
                    v2 = v2 >= 0.f ? v2 : v2 * slope;
                    v3 = v3 >= 0.f ? v3 : v3 * slope;
                    int lo = __builtin_amdgcn_cvt_pk_fp8_f32(v0, v1, 0, false);
                    int dw = __builtin_amdgcn_cvt_pk_fp8_f32(v2, v3, lo, true);
                    *(int*)(hbuf + r * 512 + ((((jb >> 4) ^ (r & 7)) << 4) | (jb & 15))) = dw;
                }
            }
        }
    }

    __syncthreads();   // hbuf fully written before Phase B

    // ---- Phase B: rowsum = sum_j tanh(h W2 + b2)[row][j] * Wg[j] ----
    float rowacc[2][16] = {};
    #pragma unroll 1
    for (int n0 = 0; n0 < 4; ++n0) {
        f32x16 acc[2][2] = {};
        #pragma unroll 1
        for (int p8 = 0; p8 < 8; ++p8) {
            int q  = n0 * 8 + p8;   // local phase 0..31
            int qn = q + 1;
            if (qn < 32)
                stage_half(W2n + (size_t)((qn >> 3) * 128) * DDIM + (qn & 7) * 64,
                           Bs[qn & 1], tid);
            int C0 = p8 * 4 + 2 * kh;   // = kt*8 + ks*4 + 2*kh
            int8v hv0, hv1;
            {
                int hrow = rh * 64 + l31, hq = hrow & 7;
                const int4* p0 = (const int4*)(hbuf + hrow * 512 + ((C0 ^ hq) << 4));
                const int4* p1 = (const int4*)(hbuf + hrow * 512 + (((C0 + 1) ^ hq) << 4));
                int4 x = *p0, y = *p1;
                hv0[0] = x.x; hv0[1] = x.y; hv0[2] = x.z; hv0[3] = x.w;
                hv0[4] = y.x; hv0[5] = y.y; hv0[6] = y.z; hv0[7] = y.w;
            }
            {
                int hrow = rh * 64 + 32 + l31, hq = hrow & 7;
                const int4* p0 = (const int4*)(hbuf + hrow * 512 + ((C0 ^ hq) << 4));
                const int4* p1 = (const int4*)(hbuf + hrow * 512 + (((C0 + 1) ^ hq) << 4));
                int4 x = *p0, y = *p1;
                hv1[0] = x.x; hv1[1] = x.y; hv1[2] = x.z; hv1[3] = x.w;
                hv1[4] = y.x; hv1[5] = y.y; hv1[6] = y.z; hv1[7] = y.w;
            }
            const unsigned char* Ts = Bs[q & 1];
            #pragma unroll
            for (int fc = 0; fc < 2; ++fc) {
                int8v wfr = load_frag_half(Ts, ch * 64 + fc * 32 + l31, kh);
                acc[0][fc] = __builtin_amdgcn_mfma_scale_f32_32x32x64_f8f6f4(
                    hv0, wfr, acc[0][fc], 0, 0, 0, 0x7F7F7F7F, 0, 0x7F7F7F7F);
                acc[1][fc] = __builtin_amdgcn_mfma_scale_f32_32x32x64_f8f6f4(
                    hv1, wfr, acc[1][fc], 0, 0, 0, 0x7F7F7F7F, 0, 0x7F7F7F7F);
            }
            __syncthreads();
        }
        #pragma unroll
        for (int fc = 0; fc < 2; ++fc) {
            int j = n0 * 128 + ch * 64 + fc * 32 + l31;
            float bias = b2[n * DDIM + j];
            float wgv = Wg[n * DDIM + j];
            #pragma unroll
            for (int rt = 0; rt < 2; ++rt)
                #pragma unroll
                for (int reg = 0; reg < 16; ++reg)
                    rowacc[rt][reg] = fmaf(fast_tanh(acc[rt][fc][reg] + bias), wgv,
                                           rowacc[rt][reg]);
        }
    }
    #pragma unroll
    for (int sh = 1; sh < 32; sh <<= 1)
        #pragma unroll
        for (int rt = 0; rt < 2; ++rt)
            #pragma unroll
            for (int reg = 0; reg < 16; ++reg)
                rowacc[rt][reg] += __shfl_xor(rowacc[rt][reg], sh);
    // combine ch-halves via lsum aliased onto hbuf (all hbuf reads are done);
    // each (ch,row) entry written by exactly one lane
    __syncthreads();
    float* lsum = (float*)hbuf;   // lsum[2][128] overlays first 1 KB of hbuf
    if (l31 == 0) {
        #pragma unroll
        for (int rt = 0; rt < 2; ++rt)
            #pragma unroll
            for (int reg = 0; reg < 16; ++reg)
                lsum[ch * 128 + rh * 64 + rt * 32 + (reg & 3) + 8 * (reg >> 2) + 4 * kh]
                    = rowacc[rt][reg];
    }
    __syncthreads();
    if (tid < 128)
        logits[(size_t)n * ROWS + m0 + tid] = lsum[tid] + lsum[128 + tid];
}

// ---------- topcand: per (n,b) top-32 of 4096 ----------
__global__ __launch_bounds__(256)
void topcand_kernel(const float* __restrict__ logits, int* __restrict__ cand,
                    float* __restrict__ ex_logit) {
    __shared__ float lv[LSEQ];
    __shared__ float cv[128];
    __shared__ int   ci[128];
    int p = blockIdx.x, n = p >> 2, b = p & 3;
    int t = threadIdx.x, lane = t & 63, w = t >> 6;
    const float* L = logits + (size_t)n * ROWS + (size_t)b * LSEQ;
    for (int i = t; i < LSEQ; i += 256) lv[i] = L[i];
    __syncthreads();
    // phase 1: each wave extracts top-32 of its 1024 (register-resident)
    float mv[16];
    int base = w * 1024;
    #pragma unroll
    for (int j = 0; j < 16; ++j) mv[j] = lv[base + j * 64 + lane];
    for (int rd = 0; rd < 32; ++rd) {
        float best = mv[0]; int bj = 0;
        #pragma unroll
        for (int j = 1; j < 16; ++j)
            if (mv[j] > best) { best = mv[j]; bj = j; }
        int bidx = base + bj * 64 + lane;
        float rv = best; int ridx = bidx;
        #pragma unroll
        for (int s = 1; s < 64; s <<= 1) {
            float ov = __shfl_xor(rv, s); int oi = __shfl_xor(ridx, s);
            if (ov > rv || (ov == rv && oi < ridx)) { rv = ov; ridx = oi; }
        }
        if (lane == 0) { cv[w * 32 + rd] = rv; ci[w * 32 + rd] = ridx; }
        if (ridx == bidx) mv[bj] = -1e30f;
    }
    __syncthreads();
    // phase 2: wave 0 merges 128 -> top-32; wave 1 zeroes ex_logit
    if (w == 0) {
        float v2[2]; int i2[2];
        #pragma unroll
        for (int k = 0; k < 2; ++k) { v2[k] = cv[k * 64 + lane]; i2[k] = ci[k * 64 + lane]; }
        for (int rd = 0; rd < 32; ++rd) {
            float best = v2[0]; int bi = i2[0]; int bk = 0;
            if (v2[1] > best || (v2[1] == best && i2[1] < bi)) { best = v2[1]; bi = i2[1]; bk = 1; }
            float rv = best; int ridx = bi;
            #pragma unroll
            for (int s = 1; s < 64; s <<= 1) {
                float ov = __shfl_xor(rv, s); int oi = __shfl_xor(ridx, s);
                if (ov > rv || (ov == rv && oi < ridx)) { rv = ov; ridx = oi; }
            }
            if (lane == 0) cand[p * NCAND + rd] = ridx;
            if (ridx == bi) v2[bk] = -1e30f;
        }
    } else if (w == 1) {
        if (lane < NCAND) ex_logit[p * NCAND + lane] = 0.f;
    }
}

// ---------- exact fp32 recompute: phase 1 (h) ----------
// grid 64p x 2ct x 8jc = 1024 blocks, 16 cands per block
__global__ __launch_bounds__(256)
void exact_h_kernel(const float* __restrict__ query,
                    const float* __restrict__ W1, const float* __restrict__ b1,
                    const int* __restrict__ cand, float* __restrict__ ex_h) {
    __shared__ float qs[DDIM][QPAD];
    __shared__ float hpart[4][16][64];
    int blk = blockIdx.x;
    int p = blk >> 4, r4 = blk & 15;
    int ct = r4 >> 3, jc = r4 & 7;
    int n = p >> 2, b = p & 3;
    int t = threadIdx.x, jj = t & 63, dg = t >> 6;
    int j = jc * 64 + jj;
    for (int c = 0; c < 16; ++c) {
        int li = cand[p * NCAND + ct * 16 + c];
        const float* qr = query + ((size_t)b * LSEQ + li) * DDIM;
        for (int d = t; d < DDIM; d += 256) qs[d][c] = qr[d];
    }
    __syncthreads();
    const float* W1n = W1 + (size_t)n * DDIM * DDIM;
    float acc[16] = {};
    for (int d = dg * 128; d < dg * 128 + 128; ++d) {
        float wvv = W1n[(size_t)d * DDIM + j];
        const float4* qv = (const float4*)&qs[d][0];
        #pragma unroll
        for (int c4 = 0; c4 < 4; ++c4) {
            float4 q4 = qv[c4];
            acc[c4 * 4 + 0] = fmaf(q4.x, wvv, acc[c4 * 4 + 0]);
            acc[c4 * 4 + 1] = fmaf(q4.y, wvv, acc[c4 * 4 + 1]);
            acc[c4 * 4 + 2] = fmaf(q4.z, wvv, acc[c4 * 4 + 2]);
            acc[c4 * 4 + 3] = fmaf(q4.w, wvv, acc[c4 * 4 + 3]);
        }
    }
    #pragma unroll
    for (int c = 0; c < 16; ++c) hpart[dg][c][jj] = acc[c];
    __syncthreads();
    const float slope = 0.01f + 0.0125f * n;
    float bias = b1[n * DDIM + j];
    for (int cc = dg; cc < 16; cc += 4) {
        float h = hpart[0][cc][jj] + hpart[1][cc][jj] + hpart[2][cc][jj]
                + hpart[3][cc][jj] + bias;
        h = h >= 0.f ? h : h * slope;
        ex_h[((size_t)p * NCAND + ct * 16 + cc) * DDIM + j] = h;
    }
}

// ---------- exact phase 2: x + exact logits ----------
__global__ __launch_bounds__(256)
void exact_x_kernel(const float* __restrict__ ex_h,
                    const float* __restrict__ W2, const float* __restrict__ b2,
                    const float* __restrict__ Wg,
                    float* __restrict__ ex_x, float* __restrict__ ex_logit) {
    __shared__ float hs[DDIM][QPAD];
    __shared__ float xpart[4][16][64];
    int blk = blockIdx.x;
    int p = blk >> 4, r4 = blk & 15;
    int ct = r4 >> 3, jc = r4 & 7;
    int n = p >> 2;
    int t = threadIdx.x, jj = t & 63, dg = t >> 6;
    int j = jc * 64 + jj;
    for (int c = 0; c < 16; ++c) {
        const float* hr = ex_h + ((size_t)p * NCAND + ct * 16 + c) * DDIM;
        for (int d = t; d < DDIM; d += 256) hs[d][c] = hr[d];
    }
    __syncthreads();
    const float* W2n = W2 + (size_t)n * DDIM * DDIM;
    float acc[16] = {};
    for (int d = dg * 128; d < dg * 128 + 128; ++d) {
        float wvv = W2n[(size_t)d * DDIM + j];
        const float4* hv = (const float4*)&hs[d][0];
        #pragma unroll
        for (int c4 = 0; c4 < 4; ++c4) {
            float4 h4 = hv[c4];
            acc[c4 * 4 + 0] = fmaf(h4.x, wvv, acc[c4 * 4 + 0]);
            acc[c4 * 4 + 1] = fmaf(h4.y, wvv, acc[c4 * 4 + 1]);
            acc[c4 * 4 + 2] = fmaf(h4.z, wvv, acc[c4 * 4 + 2]);
            acc[c4 * 4 + 3] = fmaf(h4.w, wvv, acc[c4 * 4 + 3]);
        }
    }
    #pragma unroll
    for (int c = 0; c < 16; ++c) xpart[dg][c][jj] = acc[c];
    __syncthreads();
    float bias = b2[n * DDIM + j];
    float wg = Wg[n * DDIM + j];
    for (int cc = dg; cc < 16; cc += 4) {
        float a = xpart[0][cc][jj] + xpart[1][cc][jj] + xpart[2][cc][jj]
                + xpart[3][cc][jj] + bias;
        float x = tanhf(a);
        ex_x[((size_t)p * NCAND + ct * 16 + cc) * DDIM + j] = x;
        float lp = x * wg;
        #pragma unroll
        for (int s = 1; s < 64; s <<= 1) lp += __shfl_xor(lp, s);
        if (jj == 0) atomicAdd(&ex_logit[p * NCAND + ct * 16 + cc], lp);
    }
}

// ---------- final: exact top-8 of 32, weight, combine, normalize ----------
__global__ __launch_bounds__(64)
void final_kernel(const float* __restrict__ ex_x, const float* __restrict__ ex_logit,
                  const int* __restrict__ cand, float* __restrict__ out)
{
    __shared__ float w8s[KTOP];
    __shared__ int   s8s[KTOP];
    int p = blockIdx.x, n = p >> 2, b = p & 3;
    int t = threadIdx.x;
    float myv = (t < NCAND) ? ex_logit[p * NCAND + t] : -1e30f;
    int myidx = (t < NCAND) ? cand[p * NCAND + t] : 0x7fffffff;
    float lmax = 0.f;
    for (int k = 0; k < KTOP; ++k) {
        float rv = myv; int ridx = myidx; int rl = t;
        #pragma unroll
        for (int s = 1; s < 64; s <<= 1) {
            float ov = __shfl_xor(rv, s); int oi = __shfl_xor(ridx, s); int ol = __shfl_xor(rl, s);
            if (ov > rv || (ov == rv && oi < ridx)) { rv = ov; ridx = oi; rl = ol; }
        }
        if (k == 0) lmax = rv;
        if (t == 0) { w8s[k] = __expf(rv - lmax); s8s[k] = rl; }
        if (t == rl) myv = -1e30f;
    }
    __syncthreads();
    float cvv[8];
    float sq = 0.f;
    int idx = 0;
    for (int d = t; d < DDIM; d += 64, ++idx) {
        float s = 0.f;
        #pragma unroll
        for (int k = 0; k < KTOP; ++k)
            s = fmaf(w8s[k], ex_x[((size_t)p * NCAND + s8s[k]) * DDIM + d], s);
        cvv[idx] = s;
        sq += s * s;
    }
    #pragma unroll
    for (int s = 1; s < 64; s <<= 1) sq += __shfl_xor(sq, s);
    float norm = fmaxf(sqrtf(sq), 1e-12f);
    idx = 0;
    for (int d = t; d < DDIM; d += 64, ++idx)
        out[((size_t)b * NMEM + n) * DDIM + d] = cvv[idx] / norm;
}

extern "C" void kernel_launch(void* const* d_in, const int* in_sizes, int n_in,
                              void* d_out, int out_size, void* d_ws, size_t ws_size,
                              hipStream_t stream)
{
    const float* query = (const float*)d_in[0];
    const float* W1    = (const float*)d_in[1];
    const float* b1    = (const float*)d_in[2];
    const float* W2    = (const float*)d_in[3];
    const float* b2    = (const float*)d_in[4];
    const float* Wg    = (const float*)d_in[5];
    // d_in[6] = bg cancels under softmax+normalize; d_in[7] = topk (hardcoded 8)

    char* ws = (char*)d_ws;
    const size_t MB = 1024 * 1024;
    unsigned char* Q8   = (unsigned char*)(ws);                  // 8 MB
    unsigned char* W1T8 = (unsigned char*)(ws + 8 * MB);         // 4 MB
    unsigned char* W2T8 = (unsigned char*)(ws + 12 * MB);        // 4 MB
    float* logits   = (float*)(ws + 16 * MB);                    // 1 MB
    int*   cand     = (int*)  (ws + 17 * MB);                    // 8 KB
    float* ex_logit = (float*)(ws + 17 * MB + 16384);            // 8 KB
    float* ex_h     = (float*)(ws + 20 * MB);                    // 4 MB
    float* ex_x     = (float*)(ws + 28 * MB);                    // 4 MB

    prep_kernel<<<4096, 256, 0, stream>>>(query, W1, W2, Q8, W1T8, W2T8);
    fused_mlp_kernel<<<2048, 256, 0, stream>>>(Q8, W1T8, W2T8, b1, b2, Wg, logits);
    topcand_kernel<<<64, 256, 0, stream>>>(logits, cand, ex_logit);
    exact_h_kernel<<<1024, 256, 0, stream>>>(query, W1, b1, cand, ex_h);
    exact_x_kernel<<<1024, 256, 0, stream>>>(ex_h, W2, b2, Wg, ex_x, ex_logit);
    final_kernel<<<64, 64, 0, stream>>>(ex_x, ex_logit, cand, (float*)d_out);
}

// Round 8
// 487.297 us; speedup vs baseline: 1.2598x; 1.0365x over previous
//
#include <hip/hip_runtime.h>
#include <hip/hip_bf16.h>
#include <cstdint>
#include <cstddef>

// Problem constants
#define NMEM 16
#define DDIM 512
#define BATCH 4
#define LSEQ 4096
#define ROWS 16384      // BATCH*LSEQ
#define NCAND 32        // fp8-noise safety: rank-8..32 gap ~4.5+ sigma
#define KTOP 8
#define QPAD 20

typedef __attribute__((ext_vector_type(4))) float f32x4;
typedef __attribute__((ext_vector_type(16))) float f32x16;
typedef __attribute__((ext_vector_type(8))) int int8v;

__device__ inline void gld16(const void* gptr, void* lptr) {
    __builtin_amdgcn_global_load_lds(
        (const __attribute__((address_space(1))) unsigned int*)gptr,
        (__attribute__((address_space(3))) unsigned int*)lptr,
        16, 0, 0);
}

// Polynomial tanh: t(27+t^2)/(27+9t^2), t = clamp(x,-3,3). Max abs err ~0.02,
// only used for approximate candidate logits (exact path uses tanhf).
__device__ inline float fast_tanh(float x) {
    float t = __builtin_amdgcn_fmed3f(x, -3.f, 3.f);
    float t2 = t * t;
    return t * (27.f + t2) * __builtin_amdgcn_rcpf(27.f + 9.f * t2);
}

// 32-byte MFMA fragment loaded straight from global (Q8 rows, L2/L3-resident).
__device__ inline int8v ldg_frag(const unsigned char* p) {
    int4 x = *(const int4*)p;
    int4 y = *(const int4*)(p + 16);
    int8v v;
    v[0] = x.x; v[1] = x.y; v[2] = x.z; v[3] = x.w;
    v[4] = y.x; v[5] = y.y; v[6] = y.z; v[7] = y.w;
    return v;
}

// W fragment from an 8 KB half-tile [128 rows][64 B]:
// global granule j of row r lives at slot j ^ ((r>>1)&3)  (bank-spread key)
__device__ inline int8v load_frag_half(const unsigned char* Ts, int row, int kh) {
    int key = (row >> 1) & 3;
    const int4* p0 = (const int4*)(Ts + row * 64 + ((((kh << 1) | 0) ^ key) << 4));
    const int4* p1 = (const int4*)(Ts + row * 64 + ((((kh << 1) | 1) ^ key) << 4));
    int4 x = *p0, y = *p1;
    int8v v;
    v[0] = x.x; v[1] = x.y; v[2] = x.z; v[3] = x.w;
    v[4] = y.x; v[5] = y.y; v[6] = y.z; v[7] = y.w;
    return v;
}

// coalesced stage of one [128 rows][64 B] W half-tile into an 8 KB LDS buffer.
// Wbase = &W[row0][byte-col0] of the half (rows are DDIM bytes apart).
// LDS dest is linear (gld16 requirement); source pre-swizzled to match reader.
__device__ inline void stage_half(const unsigned char* Wbase, unsigned char* dst,
                                  int tid) {
    #pragma unroll
    for (int i = 0; i < 2; ++i) {
        int c = i * 256 + tid;          // 0..511 chunk index
        int row = c >> 2, s = c & 3;
        gld16(Wbase + (size_t)row * DDIM + ((s ^ ((row >> 1) & 3)) << 4),
              dst + c * 16);
    }
}

// ---------- fused prep: Q->fp8, W1/W2 transpose->fp8 ----------
// grid: 2048 (Q) + 1024 (W1) + 1024 (W2) = 4096
__global__ __launch_bounds__(256)
void prep_kernel(const float* __restrict__ query,
                 const float* __restrict__ W1, const float* __restrict__ W2,
                 unsigned char* __restrict__ Q8,
                 unsigned char* __restrict__ W1T8, unsigned char* __restrict__ W2T8) {
    int blk = blockIdx.x, t = threadIdx.x;
    if (blk < 2048) {                       // Q convert: 16 els/thread
        size_t base = ((size_t)blk * 256 + t) * 16;
        const float4* in = (const float4*)(query + base);
        int4 o; int* op = (int*)&o;
        #pragma unroll
        for (int q = 0; q < 4; ++q) {
            float4 v = in[q];
            int lo = __builtin_amdgcn_cvt_pk_fp8_f32(v.x, v.y, 0, false);
            op[q] = __builtin_amdgcn_cvt_pk_fp8_f32(v.z, v.w, lo, true);
        }
        *(int4*)(Q8 + base) = o;
    } else {                                // W transpose+convert, 64x64 tiles
        __shared__ float tile[64][69];
        int bid = blk - 2048;               // 0..2047: 1024 per matrix
        const float* Win = W1; unsigned char* Wout = W1T8;
        if (bid >= 1024) { bid -= 1024; Win = W2; Wout = W2T8; }
        int n = bid >> 6, t64 = bid & 63;   // n in [0,16), 64 tiles of 64x64
        int dt = (t64 >> 3) << 6, jt = (t64 & 7) << 6;
        const float* inN = Win + (size_t)n * DDIM * DDIM;
        unsigned char* outN = Wout + (size_t)n * DDIM * DDIM;
        int rr = t >> 4, cc = (t & 15) * 4;
        #pragma unroll
        for (int pass = 0; pass < 4; ++pass) {
            int row = rr + pass * 16;
            float4 v = *(const float4*)(inN + (size_t)(dt + row) * DDIM + jt + cc);
            tile[row][cc] = v.x; tile[row][cc + 1] = v.y;
            tile[row][cc + 2] = v.z; tile[row][cc + 3] = v.w;
        }
        __syncthreads();
        #pragma unroll
        for (int pass = 0; pass < 4; ++pass) {
            int jl = rr + pass * 16;
            float f0 = tile[cc][jl], f1 = tile[cc + 1][jl];
            float f2 = tile[cc + 2][jl], f3 = tile[cc + 3][jl];
            int lo = __builtin_amdgcn_cvt_pk_fp8_f32(f0, f1, 0, false);
            int dw = __builtin_amdgcn_cvt_pk_fp8_f32(f2, f3, lo, true);
            *(int*)(outN + (size_t)(jt + jl) * DDIM + dt + cc) = dw;
        }
    }
}

// ---------- fused MLP (v10): counted-vmcnt depth-3 ring pipeline ----------
// grid 4096 = 256 m-tiles(64 rows) x 16 slots. Block 256 = 4 waves (rh, ch):
// wave tile = 32 rows x 64 cols. 64 phases (A:32, B:32), Bs = ring of 4
// 8 KB half-tiles; stage(P+3) issued at phase P -> ages ~2.5 phase bodies.
// End of phase: s_waitcnt vmcnt(4) (2 stages stay in flight, NEVER drain-0)
// + raw s_barrier + sched_barrier. Q-frags hoisted (8 frags = 64 VGPR,
// static idx) so the loop's VMEM stream is stage-only -> clean vmcnt count.
// v9's lesson: __syncthreads' vmcnt(0) nullified depth-1 prefetch (300us=v6).
// LDS = hbuf 32 KB + ring 32 KB + lsum 0.5 KB = 66 KB -> 2 blocks/CU.
__global__ __launch_bounds__(256, 2)
void fused_mlp_kernel(const unsigned char* __restrict__ Q8,
                      const unsigned char* __restrict__ W1T8,
                      const unsigned char* __restrict__ W2T8,
                      const float* __restrict__ b1, const float* __restrict__ b2,
                      const float* __restrict__ Wg,
                      float* __restrict__ logits)
{
    __shared__ unsigned char hbuf[64 * 512];   // 32 KB fp8 h, chunk^(row&7) swz
    __shared__ unsigned char Bs[4][8192];      // ring of W half-tiles
    __shared__ float lsum[2][64];              // per-ch partial logit rows
    const int id = blockIdx.x;
    const int n = id & 15;
    const int m0 = (id >> 4) * 64;
    const int tid = threadIdx.x, lane = tid & 63;
    const int w = tid >> 6;
    const int rh = w >> 1, ch = w & 1;
    const int l31 = lane & 31, kh = lane >> 5;
    const unsigned char* W1n = W1T8 + (size_t)n * DDIM * DDIM;
    const unsigned char* W2n = W2T8 + (size_t)n * DDIM * DDIM;
    const float slope = 0.01f + 0.0125f * n;
    const unsigned char* Aq0 = Q8 + (size_t)(m0 + rh * 32 + l31) * DDIM + kh * 32;

    // prologue: hoist ALL 8 Q-frags (32 rows/wave -> 64 VGPR, static index),
    // then prime the ring with stages P=0,1,2. Q loads are OLDER than stages,
    // so vmcnt(4) below drains Q + stage(0), leaves stage(1),(2) in flight.
    int8v avq[8];
    #pragma unroll
    for (int qa = 0; qa < 8; ++qa)
        avq[qa] = ldg_frag(Aq0 + qa * 64);
    stage_half(W1n,       Bs[0], tid);
    stage_half(W1n + 64,  Bs[1], tid);
    stage_half(W1n + 128, Bs[2], tid);
    asm volatile("s_waitcnt vmcnt(4)" ::: "memory");
    __builtin_amdgcn_s_barrier();
    __builtin_amdgcn_sched_barrier(0);

    // ---- Phase A: h^T = (Q W1)^T (swapped operands); lane holds Q-row
    //      r = rh*32+l31, cols j = n0*128+ch*64+fc*32+(reg&3)+8(reg>>2)+4kh
    #pragma unroll 1
    for (int n0 = 0; n0 < 4; ++n0) {
        f32x16 acc[2] = {};   // [fc], static indices
        #pragma unroll
        for (int p8 = 0; p8 < 8; ++p8) {
            const int P = n0 * 8 + p8, Pn = P + 3;   // Pn <= 34 < 64 always
            const unsigned char* nsrc = (Pn < 32)
                ? W1n + (size_t)((Pn >> 3) * 128) * DDIM + (Pn & 7) * 64
                : W2n + (size_t)(((Pn - 32) >> 3) * 128) * DDIM + ((Pn - 32) & 7) * 64;
            stage_half(nsrc, Bs[Pn & 3], tid);
            const unsigned char* Ts = Bs[P & 3];
            int8v wfr0 = load_frag_half(Ts, ch * 64 + l31, kh);
            int8v wfr1 = load_frag_half(Ts, ch * 64 + 32 + l31, kh);
            acc[0] = __builtin_amdgcn_mfma_scale_f32_32x32x64_f8f6f4(
                wfr0, avq[p8], acc[0], 0, 0, 0, 0x7F7F7F7F, 0, 0x7F7F7F7F);
            acc[1] = __builtin_amdgcn_mfma_scale_f32_32x32x64_f8f6f4(
                wfr1, avq[p8], acc[1], 0, 0, 0, 0x7F7F7F7F, 0, 0x7F7F7F7F);
            // publish stage(P+1): newer in flight = stage(P+2),(P+3) = 4 ops
            asm volatile("s_waitcnt vmcnt(4)" ::: "memory");
            __builtin_amdgcn_s_barrier();
            __builtin_amdgcn_sched_barrier(0);
        }
        // epilogue: bias + leaky + fp8-pack, one ds_write_b32 per reg-quad
        #pragma unroll
        for (int fc = 0; fc < 2; ++fc) {
            int r = rh * 32 + l31;
            #pragma unroll
            for (int q = 0; q < 4; ++q) {
                int jb = n0 * 128 + ch * 64 + fc * 32 + 8 * q + 4 * kh;
                float4 bias = *(const float4*)(b1 + n * DDIM + jb);
                float v0 = acc[fc][4 * q + 0] + bias.x;
                float v1 = acc[fc][4 * q + 1] + bias.y;
                float v2 = acc[fc][4 * q + 2] + bias.z;
                float v3 = acc[fc][4 * q + 3] + bias.w;
                v0 = v0 >= 0.f ? v0 : v0 * slope;
                v1 = v1 >= 0.f ? v1 : v1 * slope;
                v2 = v2 >= 0.f ? v2 : v2 * slope;
                v3 = v3 >= 0.f ? v3 : v3 * slope;
                int lo = __builtin_amdgcn_cvt_pk_fp8_f32(v0, v1, 0, false);
                int dw = __builtin_amdgcn_cvt_pk_fp8_f32(v2, v3, lo, true);
                *(int*)(hbuf + r * 512 + ((((jb >> 4) ^ (r & 7)) << 4) | (jb & 15))) = dw;
            }
        }
    }

    __syncthreads();   // A->B: publish hbuf (also drains in-flight B stages)

    // ---- Phase B: rowsum = sum_j tanh(h W2 + b2)[row][j] * Wg[j] ----
    float rowacc[16] = {};
    #pragma unroll 1
    for (int n0 = 0; n0 < 4; ++n0) {
        f32x16 acc[2] = {};
        #pragma unroll 1
        for (int p8 = 0; p8 < 8; ++p8) {
            const int P = 32 + n0 * 8 + p8, Pn = P + 3;
            if (Pn < 64)
                stage_half(W2n + (size_t)(((Pn - 32) >> 3) * 128) * DDIM
                               + ((Pn - 32) & 7) * 64,
                           Bs[Pn & 3], tid);
            int hrow = rh * 32 + l31, hq = hrow & 7;
            int C0 = p8 * 4 + 2 * kh;
            int8v hv;
            {
                const int4* p0 = (const int4*)(hbuf + hrow * 512 + ((C0 ^ hq) << 4));
                const int4* p1 = (const int4*)(hbuf + hrow * 512 + (((C0 + 1) ^ hq) << 4));
                int4 x = *p0, y = *p1;
                hv[0] = x.x; hv[1] = x.y; hv[2] = x.z; hv[3] = x.w;
                hv[4] = y.x; hv[5] = y.y; hv[6] = y.z; hv[7] = y.w;
            }
            const unsigned char* Ts = Bs[P & 3];
            int8v wfr0 = load_frag_half(Ts, ch * 64 + l31, kh);
            int8v wfr1 = load_frag_half(Ts, ch * 64 + 32 + l31, kh);
            acc[0] = __builtin_amdgcn_mfma_scale_f32_32x32x64_f8f6f4(
                hv, wfr0, acc[0], 0, 0, 0, 0x7F7F7F7F, 0, 0x7F7F7F7F);
            acc[1] = __builtin_amdgcn_mfma_scale_f32_32x32x64_f8f6f4(
                hv, wfr1, acc[1], 0, 0, 0, 0x7F7F7F7F, 0, 0x7F7F7F7F);
            if (Pn < 64) asm volatile("s_waitcnt vmcnt(4)" ::: "memory");
            else         asm volatile("s_waitcnt vmcnt(0)" ::: "memory");
            __builtin_amdgcn_s_barrier();
            __builtin_amdgcn_sched_barrier(0);
        }
        #pragma unroll
        for (int fc = 0; fc < 2; ++fc) {
            int j = n0 * 128 + ch * 64 + fc * 32 + l31;
            float bias = b2[n * DDIM + j];
            float wgv = Wg[n * DDIM + j];
            #pragma unroll
            for (int reg = 0; reg < 16; ++reg)
                rowacc[reg] = fmaf(fast_tanh(acc[fc][reg] + bias), wgv, rowacc[reg]);
        }
    }
    #pragma unroll
    for (int sh = 1; sh < 32; sh <<= 1)
        #pragma unroll
        for (int reg = 0; reg < 16; ++reg)
            rowacc[reg] += __shfl_xor(rowacc[reg], sh);
    // combine ch-halves: each (ch,row) entry written by exactly one lane
    if (l31 == 0) {
        #pragma unroll
        for (int reg = 0; reg < 16; ++reg)
            lsum[ch][rh * 32 + (reg & 3) + 8 * (reg >> 2) + 4 * kh] = rowacc[reg];
    }
    __syncthreads();
    if (tid < 64)
        logits[(size_t)n * ROWS + m0 + tid] = lsum[0][tid] + lsum[1][tid];
}

// ---------- topcand: per (n,b) top-32 of 4096 ----------
__global__ __launch_bounds__(256)
void topcand_kernel(const float* __restrict__ logits, int* __restrict__ cand,
                    float* __restrict__ ex_logit) {
    __shared__ float lv[LSEQ];
    __shared__ float cv[128];
    __shared__ int   ci[128];
    int p = blockIdx.x, n = p >> 2, b = p & 3;
    int t = threadIdx.x, lane = t & 63, w = t >> 6;
    const float* L = logits + (size_t)n * ROWS + (size_t)b * LSEQ;
    for (int i = t; i < LSEQ; i += 256) lv[i] = L[i];
    __syncthreads();
    // phase 1: each wave extracts top-32 of its 1024 (register-resident)
    float mv[16];
    int base = w * 1024;
    #pragma unroll
    for (int j = 0; j < 16; ++j) mv[j] = lv[base + j * 64 + lane];
    for (int rd = 0; rd < 32; ++rd) {
        float best = mv[0]; int bj = 0;
        #pragma unroll
        for (int j = 1; j < 16; ++j)
            if (mv[j] > best) { best = mv[j]; bj = j; }
        int bidx = base + bj * 64 + lane;
        float rv = best; int ridx = bidx;
        #pragma unroll
        for (int s = 1; s < 64; s <<= 1) {
            float ov = __shfl_xor(rv, s); int oi = __shfl_xor(ridx, s);
            if (ov > rv || (ov == rv && oi < ridx)) { rv = ov; ridx = oi; }
        }
        if (lane == 0) { cv[w * 32 + rd] = rv; ci[w * 32 + rd] = ridx; }
        if (ridx == bidx) mv[bj] = -1e30f;
    }
    __syncthreads();
    // phase 2: wave 0 merges 128 -> top-32; wave 1 zeroes ex_logit
    if (w == 0) {
        float v2[2]; int i2[2];
        #pragma unroll
        for (int k = 0; k < 2; ++k) { v2[k] = cv[k * 64 + lane]; i2[k] = ci[k * 64 + lane]; }
        for (int rd = 0; rd < 32; ++rd) {
            float best = v2[0]; int bi = i2[0]; int bk = 0;
            if (v2[1] > best || (v2[1] == best && i2[1] < bi)) { best = v2[1]; bi = i2[1]; bk = 1; }
            float rv = best; int ridx = bi;
            #pragma unroll
            for (int s = 1; s < 64; s <<= 1) {
                float ov = __shfl_xor(rv, s); int oi = __shfl_xor(ridx, s);
                if (ov > rv || (ov == rv && oi < ridx)) { rv = ov; ridx = oi; }
            }
            if (lane == 0) cand[p * NCAND + rd] = ridx;
            if (ridx == bi) v2[bk] = -1e30f;
        }
    } else if (w == 1) {
        if (lane < NCAND) ex_logit[p * NCAND + lane] = 0.f;
    }
}

// ---------- exact fp32 recompute: phase 1 (h) ----------
// grid 64p x 2ct x 8jc = 1024 blocks, 16 cands per block
__global__ __launch_bounds__(256)
void exact_h_kernel(const float* __restrict__ query,
                    const float* __restrict__ W1, const float* __restrict__ b1,
                    const int* __restrict__ cand, float* __restrict__ ex_h) {
    __shared__ float qs[DDIM][QPAD];
    __shared__ float hpart[4][16][64];
    int blk = blockIdx.x;
    int p = blk >> 4, r4 = blk & 15;
    int ct = r4 >> 3, jc = r4 & 7;
    int n = p >> 2, b = p & 3;
    int t = threadIdx.x, jj = t & 63, dg = t >> 6;
    int j = jc * 64 + jj;
    for (int c = 0; c < 16; ++c) {
        int li = cand[p * NCAND + ct * 16 + c];
        const float* qr = query + ((size_t)b * LSEQ + li) * DDIM;
        for (int d = t; d < DDIM; d += 256) qs[d][c] = qr[d];
    }
    __syncthreads();
    const float* W1n = W1 + (size_t)n * DDIM * DDIM;
    float acc[16] = {};
    for (int d = dg * 128; d < dg * 128 + 128; ++d) {
        float wvv = W1n[(size_t)d * DDIM + j];
        const float4* qv = (const float4*)&qs[d][0];
        #pragma unroll
        for (int c4 = 0; c4 < 4; ++c4) {
            float4 q4 = qv[c4];
            acc[c4 * 4 + 0] = fmaf(q4.x, wvv, acc[c4 * 4 + 0]);
            acc[c4 * 4 + 1] = fmaf(q4.y, wvv, acc[c4 * 4 + 1]);
            acc[c4 * 4 + 2] = fmaf(q4.z, wvv, acc[c4 * 4 + 2]);
            acc[c4 * 4 + 3] = fmaf(q4.w, wvv, acc[c4 * 4 + 3]);
        }
    }
    #pragma unroll
    for (int c = 0; c < 16; ++c) hpart[dg][c][jj] = acc[c];
    __syncthreads();
    const float slope = 0.01f + 0.0125f * n;
    float bias = b1[n * DDIM + j];
    for (int cc = dg; cc < 16; cc += 4) {
        float h = hpart[0][cc][jj] + hpart[1][cc][jj] + hpart[2][cc][jj]
                + hpart[3][cc][jj] + bias;
        h = h >= 0.f ? h : h * slope;
        ex_h[((size_t)p * NCAND + ct * 16 + cc) * DDIM + j] = h;
    }
}

// ---------- exact phase 2: x + exact logits ----------
__global__ __launch_bounds__(256)
void exact_x_kernel(const float* __restrict__ ex_h,
                    const float* __restrict__ W2, const float* __restrict__ b2,
                    const float* __restrict__ Wg,
                    float* __restrict__ ex_x, float* __restrict__ ex_logit) {
    __shared__ float hs[DDIM][QPAD];
    __shared__ float xpart[4][16][64];
    int blk = blockIdx.x;
    int p = blk >> 4, r4 = blk & 15;
    int ct = r4 >> 3, jc = r4 & 7;
    int n = p >> 2;
    int t = threadIdx.x, jj = t & 63, dg = t >> 6;
    int j = jc * 64 + jj;
    for (int c = 0; c < 16; ++c) {
        const float* hr = ex_h + ((size_t)p * NCAND + ct * 16 + c) * DDIM;
        for (int d = t; d < DDIM; d += 256) hs[d][c] = hr[d];
    }
    __syncthreads();
    const float* W2n = W2 + (size_t)n * DDIM * DDIM;
    float acc[16] = {};
    for (int d = dg * 128; d < dg * 128 + 128; ++d) {
        float wvv = W2n[(size_t)d * DDIM + j];
        const float4* hv = (const float4*)&hs[d][0];
        #pragma unroll
        for (int c4 = 0; c4 < 4; ++c4) {
            float4 h4 = hv[c4];
            acc[c4 * 4 + 0] = fmaf(h4.x, wvv, acc[c4 * 4 + 0]);
            acc[c4 * 4 + 1] = fmaf(h4.y, wvv, acc[c4 * 4 + 1]);
            acc[c4 * 4 + 2] = fmaf(h4.z, wvv, acc[c4 * 4 + 2]);
            acc[c4 * 4 + 3] = fmaf(h4.w, wvv, acc[c4 * 4 + 3]);
        }
    }
    #pragma unroll
    for (int c = 0; c < 16; ++c) xpart[dg][c][jj] = acc[c];
    __syncthreads();
    float bias = b2[n * DDIM + j];
    float wg = Wg[n * DDIM + j];
    for (int cc = dg; cc < 16; cc += 4) {
        float a = xpart[0][cc][jj] + xpart[1][cc][jj] + xpart[2][cc][jj]
                + xpart[3][cc][jj] + bias;
        float x = tanhf(a);
        ex_x[((size_t)p * NCAND + ct * 16 + cc) * DDIM + j] = x;
        float lp = x * wg;
        #pragma unroll
        for (int s = 1; s < 64; s <<= 1) lp += __shfl_xor(lp, s);
        if (jj == 0) atomicAdd(&ex_logit[p * NCAND + ct * 16 + cc], lp);
    }
}

// ---------- final: exact top-8 of 32, weight, combine, normalize ----------
__global__ __launch_bounds__(64)
void final_kernel(const float* __restrict__ ex_x, const float* __restrict__ ex_logit,
                  const int* __restrict__ cand, float* __restrict__ out)
{
    __shared__ float w8s[KTOP];
    __shared__ int   s8s[KTOP];
    int p = blockIdx.x, n = p >> 2, b = p & 3;
    int t = threadIdx.x;
    float myv = (t < NCAND) ? ex_logit[p * NCAND + t] : -1e30f;
    int myidx = (t < NCAND) ? cand[p * NCAND + t] : 0x7fffffff;
    float lmax = 0.f;
    for (int k = 0; k < KTOP; ++k) {
        float rv = myv; int ridx = myidx; int rl = t;
        #pragma unroll
        for (int s = 1; s < 64; s <<= 1) {
            float ov = __shfl_xor(rv, s); int oi = __shfl_xor(ridx, s); int ol = __shfl_xor(rl, s);
            if (ov > rv || (ov == rv && oi < ridx)) { rv = ov; ridx = oi; rl = ol; }
        }
        if (k == 0) lmax = rv;
        if (t == 0) { w8s[k] = __expf(rv - lmax); s8s[k] = rl; }
        if (t == rl) myv = -1e30f;
    }
    __syncthreads();
    float cvv[8];
    float sq = 0.f;
    int idx = 0;
    for (int d = t; d < DDIM; d += 64, ++idx) {
        float s = 0.f;
        #pragma unroll
        for (int k = 0; k < KTOP; ++k)
            s = fmaf(w8s[k], ex_x[((size_t)p * NCAND + s8s[k]) * DDIM + d], s);
        cvv[idx] = s;
        sq += s * s;
    }
    #pragma unroll
    for (int s = 1; s < 64; s <<= 1) sq += __shfl_xor(sq, s);
    float norm = fmaxf(sqrtf(sq), 1e-12f);
    idx = 0;
    for (int d = t; d < DDIM; d += 64, ++idx)
        out[((size_t)b * NMEM + n) * DDIM + d] = cvv[idx] / norm;
}

extern "C" void kernel_launch(void* const* d_in, const int* in_sizes, int n_in,
                              void* d_out, int out_size, void* d_ws, size_t ws_size,
                              hipStream_t stream)
{
    const float* query = (const float*)d_in[0];
    const float* W1    = (const float*)d_in[1];
    const float* b1    = (const float*)d_in[2];
    const float* W2    = (const float*)d_in[3];
    const float* b2    = (const float*)d_in[4];
    const float* Wg    = (const float*)d_in[5];
    // d_in[6] = bg cancels under softmax+normalize; d_in[7] = topk (hardcoded 8)

    char* ws = (char*)d_ws;
    const size_t MB = 1024 * 1024;
    unsigned char* Q8   = (unsigned char*)(ws);                  // 8 MB
    unsigned char* W1T8 = (unsigned char*)(ws + 8 * MB);         // 4 MB
    unsigned char* W2T8 = (unsigned char*)(ws + 12 * MB);        // 4 MB
    float* logits   = (float*)(ws + 16 * MB);                    // 1 MB
    int*   cand     = (int*)  (ws + 17 * MB);                    // 8 KB
    float* ex_logit = (float*)(ws + 17 * MB + 16384);            // 8 KB
    float* ex_h     = (float*)(ws + 20 * MB);                    // 4 MB
    float* ex_x     = (float*)(ws + 28 * MB);                    // 4 MB

    prep_kernel<<<4096, 256, 0, stream>>>(query, W1, W2, Q8, W1T8, W2T8);
    fused_mlp_kernel<<<4096, 256, 0, stream>>>(Q8, W1T8, W2T8, b1, b2, Wg, logits);
    topcand_kernel<<<64, 256, 0, stream>>>(logits, cand, ex_logit);
    exact_h_kernel<<<1024, 256, 0, stream>>>(query, W1, b1, cand, ex_h);
    exact_x_kernel<<<1024, 256, 0, stream>>>(ex_h, W2, b2, Wg, ex_x, ex_logit);
    final_kernel<<<64, 64, 0, stream>>>(ex_x, ex_logit, cand, (float*)d_out);
}

// Round 9
// 460.637 us; speedup vs baseline: 1.3327x; 1.0579x over previous
//
#include <hip/hip_runtime.h>
#include <hip/hip_bf16.h>
#include <cstdint>
#include <cstddef>

// Problem constants
#define NMEM 16
#define DDIM 512
#define BATCH 4
#define LSEQ 4096
#define ROWS 16384      // BATCH*LSEQ
#define NCAND 32        // fp8-noise safety: rank-8..32 gap ~4.5+ sigma
#define KTOP 8
#define QPAD 20

typedef __attribute__((ext_vector_type(4))) float f32x4;
typedef __attribute__((ext_vector_type(16))) float f32x16;
typedef __attribute__((ext_vector_type(8))) int int8v;

__device__ inline void gld16(const void* gptr, void* lptr) {
    __builtin_amdgcn_global_load_lds(
        (const __attribute__((address_space(1))) unsigned int*)gptr,
        (__attribute__((address_space(3))) unsigned int*)lptr,
        16, 0, 0);
}

// Polynomial tanh: t(27+t^2)/(27+9t^2), t = clamp(x,-3,3). Max abs err ~0.02,
// only used for approximate candidate logits (exact path uses tanhf).
__device__ inline float fast_tanh(float x) {
    float t = __builtin_amdgcn_fmed3f(x, -3.f, 3.f);
    float t2 = t * t;
    return t * (27.f + t2) * __builtin_amdgcn_rcpf(27.f + 9.f * t2);
}

// 32-byte MFMA fragment loaded straight from global (Q8 rows, L2/L3-resident).
__device__ inline int8v ldg_frag(const unsigned char* p) {
    int4 x = *(const int4*)p;
    int4 y = *(const int4*)(p + 16);
    int8v v;
    v[0] = x.x; v[1] = x.y; v[2] = x.z; v[3] = x.w;
    v[4] = y.x; v[5] = y.y; v[6] = y.z; v[7] = y.w;
    return v;
}

// W fragment from an 8 KB half-tile [128 rows][64 B]:
// global granule j of row r lives at slot j ^ ((r>>1)&3)  (bank-spread key)
__device__ inline int8v load_frag_half(const unsigned char* Ts, int row, int kh) {
    int key = (row >> 1) & 3;
    const int4* p0 = (const int4*)(Ts + row * 64 + ((((kh << 1) | 0) ^ key) << 4));
    const int4* p1 = (const int4*)(Ts + row * 64 + ((((kh << 1) | 1) ^ key) << 4));
    int4 x = *p0, y = *p1;
    int8v v;
    v[0] = x.x; v[1] = x.y; v[2] = x.z; v[3] = x.w;
    v[4] = y.x; v[5] = y.y; v[6] = y.z; v[7] = y.w;
    return v;
}

// coalesced stage of one [128 rows][64 B] W half-tile into an 8 KB LDS buffer.
// Wbase = &W[row0][byte-col0] of the half (rows are DDIM bytes apart).
// LDS dest is linear (gld16 requirement); source pre-swizzled to match reader.
__device__ inline void stage_half(const unsigned char* Wbase, unsigned char* dst,
                                  int tid) {
    #pragma unroll
    for (int i = 0; i < 2; ++i) {
        int c = i * 256 + tid;          // 0..511 chunk index
        int row = c >> 2, s = c & 3;
        gld16(Wbase + (size_t)row * DDIM + ((s ^ ((row >> 1) & 3)) << 4),
              dst + c * 16);
    }
}

// ---------- fused prep: Q->fp8, W1/W2 transpose->fp8 ----------
// grid: 2048 (Q) + 1024 (W1) + 1024 (W2) = 4096
__global__ __launch_bounds__(256)
void prep_kernel(const float* __restrict__ query,
                 const float* __restrict__ W1, const float* __restrict__ W2,
                 unsigned char* __restrict__ Q8,
                 unsigned char* __restrict__ W1T8, unsigned char* __restrict__ W2T8) {
    int blk = blockIdx.x, t = threadIdx.x;
    if (blk < 2048) {                       // Q convert: 16 els/thread
        size_t base = ((size_t)blk * 256 + t) * 16;
        const float4* in = (const float4*)(query + base);
        int4 o; int* op = (int*)&o;
        #pragma unroll
        for (int q = 0; q < 4; ++q) {
            float4 v = in[q];
            int lo = __builtin_amdgcn_cvt_pk_fp8_f32(v.x, v.y, 0, false);
            op[q] = __builtin_amdgcn_cvt_pk_fp8_f32(v.z, v.w, lo, true);
        }
        *(int4*)(Q8 + base) = o;
    } else {                                // W transpose+convert, 64x64 tiles
        __shared__ float tile[64][69];
        int bid = blk - 2048;               // 0..2047: 1024 per matrix
        const float* Win = W1; unsigned char* Wout = W1T8;
        if (bid >= 1024) { bid -= 1024; Win = W2; Wout = W2T8; }
        int n = bid >> 6, t64 = bid & 63;   // n in [0,16), 64 tiles of 64x64
        int dt = (t64 >> 3) << 6, jt = (t64 & 7) << 6;
        const float* inN = Win + (size_t)n * DDIM * DDIM;
        unsigned char* outN = Wout + (size_t)n * DDIM * DDIM;
        int rr = t >> 4, cc = (t & 15) * 4;
        #pragma unroll
        for (int pass = 0; pass < 4; ++pass) {
            int row = rr + pass * 16;
            float4 v = *(const float4*)(inN + (size_t)(dt + row) * DDIM + jt + cc);
            tile[row][cc] = v.x; tile[row][cc + 1] = v.y;
            tile[row][cc + 2] = v.z; tile[row][cc + 3] = v.w;
        }
        __syncthreads();
        #pragma unroll
        for (int pass = 0; pass < 4; ++pass) {
            int jl = rr + pass * 16;
            float f0 = tile[cc][jl], f1 = tile[cc + 1][jl];
            float f2 = tile[cc + 2][jl], f3 = tile[cc + 3][jl];
            int lo = __builtin_amdgcn_cvt_pk_fp8_f32(f0, f1, 0, false);
            int dw = __builtin_amdgcn_cvt_pk_fp8_f32(f2, f3, lo, true);
            *(int*)(outN + (size_t)(jt + jl) * DDIM + dt + cc) = dw;
        }
    }
}

// ---------- fused MLP (v11): 3 blocks/CU via small LDS; aged dbuf stage ----
// grid 4096 = 256 m-tiles(64 rows) x 16 slots. Block 256 = 4 waves (rh, ch):
// wave tile = 32 rows x 64 cols. 64 phases (A:32, B:32), Bs = 2 x 8 KB
// double buffer; stage(P+1) issued at TOP of phase P (ages full phase body
// before the barrier drain). Q-frags hoisted (8 frags = 64 VGPR, static idx).
// v10 lesson: counted-vmcnt depth-3 at 2 blocks/CU gave only +4% — the kernel
// is latency/sync-bound at 7.3 waves/CU. This version buys TLP instead:
// LDS = hbuf 32 KB + Bs 16 KB + lsum 0.5 KB = 48.5 KB -> 3 blocks/CU
// (12 waves), __launch_bounds__(256,3) (VGPR cap 168; v10 used 104).
__global__ __launch_bounds__(256, 3)
void fused_mlp_kernel(const unsigned char* __restrict__ Q8,
                      const unsigned char* __restrict__ W1T8,
                      const unsigned char* __restrict__ W2T8,
                      const float* __restrict__ b1, const float* __restrict__ b2,
                      const float* __restrict__ Wg,
                      float* __restrict__ logits)
{
    __shared__ unsigned char hbuf[64 * 512];   // 32 KB fp8 h, chunk^(row&7) swz
    __shared__ unsigned char Bs[2][8192];      // double-buffered W half-tiles
    __shared__ float lsum[2][64];              // per-ch partial logit rows
    const int id = blockIdx.x;
    const int n = id & 15;
    const int m0 = (id >> 4) * 64;
    const int tid = threadIdx.x, lane = tid & 63;
    const int w = tid >> 6;
    const int rh = w >> 1, ch = w & 1;
    const int l31 = lane & 31, kh = lane >> 5;
    const unsigned char* W1n = W1T8 + (size_t)n * DDIM * DDIM;
    const unsigned char* W2n = W2T8 + (size_t)n * DDIM * DDIM;
    const float slope = 0.01f + 0.0125f * n;
    const unsigned char* Aq0 = Q8 + (size_t)(m0 + rh * 32 + l31) * DDIM + kh * 32;

    // prologue: hoist ALL 8 Q-frags (32 rows/wave, static index), stage(0)
    int8v avq[8];
    #pragma unroll
    for (int qa = 0; qa < 8; ++qa)
        avq[qa] = ldg_frag(Aq0 + qa * 64);
    stage_half(W1n, Bs[0], tid);
    __syncthreads();

    // ---- Phase A: h^T = (Q W1)^T (swapped operands); lane holds Q-row
    //      r = rh*32+l31, cols j = n0*128+ch*64+fc*32+(reg&3)+8(reg>>2)+4kh
    #pragma unroll 1
    for (int n0 = 0; n0 < 4; ++n0) {
        f32x16 acc[2] = {};   // [fc], static indices
        #pragma unroll
        for (int p8 = 0; p8 < 8; ++p8) {
            const int P = n0 * 8 + p8, Pn = P + 1;   // Pn==32 => W2 half 0
            const unsigned char* nsrc = (Pn < 32)
                ? W1n + (size_t)((Pn >> 3) * 128) * DDIM + (Pn & 7) * 64
                : W2n;
            stage_half(nsrc, Bs[Pn & 1], tid);   // ages the full phase body
            const unsigned char* Ts = Bs[P & 1];
            int8v wfr0 = load_frag_half(Ts, ch * 64 + l31, kh);
            int8v wfr1 = load_frag_half(Ts, ch * 64 + 32 + l31, kh);
            acc[0] = __builtin_amdgcn_mfma_scale_f32_32x32x64_f8f6f4(
                wfr0, avq[p8], acc[0], 0, 0, 0, 0x7F7F7F7F, 0, 0x7F7F7F7F);
            acc[1] = __builtin_amdgcn_mfma_scale_f32_32x32x64_f8f6f4(
                wfr1, avq[p8], acc[1], 0, 0, 0, 0x7F7F7F7F, 0, 0x7F7F7F7F);
            __syncthreads();   // publish stage(P+1); other 2 blocks cover drain
        }
        // epilogue: bias + leaky + fp8-pack, one ds_write_b32 per reg-quad
        #pragma unroll
        for (int fc = 0; fc < 2; ++fc) {
            int r = rh * 32 + l31;
            #pragma unroll
            for (int q = 0; q < 4; ++q) {
                int jb = n0 * 128 + ch * 64 + fc * 32 + 8 * q + 4 * kh;
                float4 bias = *(const float4*)(b1 + n * DDIM + jb);
                float v0 = acc[fc][4 * q + 0] + bias.x;
                float v1 = acc[fc][4 * q + 1] + bias.y;
                float v2 = acc[fc][4 * q + 2] + bias.z;
                float v3 = acc[fc][4 * q + 3] + bias.w;
                v0 = v0 >= 0.f ? v0 : v0 * slope;
                v1 = v1 >= 0.f ? v1 : v1 * slope;
                v2 = v2 >= 0.f ? v2 : v2 * slope;
                v3 = v3 >= 0.f ? v3 : v3 * slope;
                int lo = __builtin_amdgcn_cvt_pk_fp8_f32(v0, v1, 0, false);
                int dw = __builtin_amdgcn_cvt_pk_fp8_f32(v2, v3, lo, true);
                *(int*)(hbuf + r * 512 + ((((jb >> 4) ^ (r & 7)) << 4) | (jb & 15))) = dw;
            }
        }
    }

    __syncthreads();   // A->B: publish hbuf (also drains in-flight stage(32))

    // ---- Phase B: rowsum = sum_j tanh(h W2 + b2)[row][j] * Wg[j] ----
    float rowacc[16] = {};
    #pragma unroll 1
    for (int n0 = 0; n0 < 4; ++n0) {
        f32x16 acc[2] = {};
        #pragma unroll 1
        for (int p8 = 0; p8 < 8; ++p8) {
            const int P = 32 + n0 * 8 + p8, Pn = P + 1;
            if (Pn < 64)
                stage_half(W2n + (size_t)(((Pn - 32) >> 3) * 128) * DDIM
                               + ((Pn - 32) & 7) * 64,
                           Bs[Pn & 1], tid);
            int hrow = rh * 32 + l31, hq = hrow & 7;
            int C0 = p8 * 4 + 2 * kh;
            int8v hv;
            {
                const int4* p0 = (const int4*)(hbuf + hrow * 512 + ((C0 ^ hq) << 4));
                const int4* p1 = (const int4*)(hbuf + hrow * 512 + (((C0 + 1) ^ hq) << 4));
                int4 x = *p0, y = *p1;
                hv[0] = x.x; hv[1] = x.y; hv[2] = x.z; hv[3] = x.w;
                hv[4] = y.x; hv[5] = y.y; hv[6] = y.z; hv[7] = y.w;
            }
            const unsigned char* Ts = Bs[P & 1];
            int8v wfr0 = load_frag_half(Ts, ch * 64 + l31, kh);
            int8v wfr1 = load_frag_half(Ts, ch * 64 + 32 + l31, kh);
            acc[0] = __builtin_amdgcn_mfma_scale_f32_32x32x64_f8f6f4(
                hv, wfr0, acc[0], 0, 0, 0, 0x7F7F7F7F, 0, 0x7F7F7F7F);
            acc[1] = __builtin_amdgcn_mfma_scale_f32_32x32x64_f8f6f4(
                hv, wfr1, acc[1], 0, 0, 0, 0x7F7F7F7F, 0, 0x7F7F7F7F);
            __syncthreads();
        }
        #pragma unroll
        for (int fc = 0; fc < 2; ++fc) {
            int j = n0 * 128 + ch * 64 + fc * 32 + l31;
            float bias = b2[n * DDIM + j];
            float wgv = Wg[n * DDIM + j];
            #pragma unroll
            for (int reg = 0; reg < 16; ++reg)
                rowacc[reg] = fmaf(fast_tanh(acc[fc][reg] + bias), wgv, rowacc[reg]);
        }
    }
    #pragma unroll
    for (int sh = 1; sh < 32; sh <<= 1)
        #pragma unroll
        for (int reg = 0; reg < 16; ++reg)
            rowacc[reg] += __shfl_xor(rowacc[reg], sh);
    // combine ch-halves: each (ch,row) entry written by exactly one lane
    if (l31 == 0) {
        #pragma unroll
        for (int reg = 0; reg < 16; ++reg)
            lsum[ch][rh * 32 + (reg & 3) + 8 * (reg >> 2) + 4 * kh] = rowacc[reg];
    }
    __syncthreads();
    if (tid < 64)
        logits[(size_t)n * ROWS + m0 + tid] = lsum[0][tid] + lsum[1][tid];
}

// ---------- topcand: per (n,b) top-32 of 4096 ----------
__global__ __launch_bounds__(256)
void topcand_kernel(const float* __restrict__ logits, int* __restrict__ cand,
                    float* __restrict__ ex_logit) {
    __shared__ float lv[LSEQ];
    __shared__ float cv[128];
    __shared__ int   ci[128];
    int p = blockIdx.x, n = p >> 2, b = p & 3;
    int t = threadIdx.x, lane = t & 63, w = t >> 6;
    const float* L = logits + (size_t)n * ROWS + (size_t)b * LSEQ;
    for (int i = t; i < LSEQ; i += 256) lv[i] = L[i];
    __syncthreads();
    // phase 1: each wave extracts top-32 of its 1024 (register-resident)
    float mv[16];
    int base = w * 1024;
    #pragma unroll
    for (int j = 0; j < 16; ++j) mv[j] = lv[base + j * 64 + lane];
    for (int rd = 0; rd < 32; ++rd) {
        float best = mv[0]; int bj = 0;
        #pragma unroll
        for (int j = 1; j < 16; ++j)
            if (mv[j] > best) { best = mv[j]; bj = j; }
        int bidx = base + bj * 64 + lane;
        float rv = best; int ridx = bidx;
        #pragma unroll
        for (int s = 1; s < 64; s <<= 1) {
            float ov = __shfl_xor(rv, s); int oi = __shfl_xor(ridx, s);
            if (ov > rv || (ov == rv && oi < ridx)) { rv = ov; ridx = oi; }
        }
        if (lane == 0) { cv[w * 32 + rd] = rv; ci[w * 32 + rd] = ridx; }
        if (ridx == bidx) mv[bj] = -1e30f;
    }
    __syncthreads();
    // phase 2: wave 0 merges 128 -> top-32; wave 1 zeroes ex_logit
    if (w == 0) {
        float v2[2]; int i2[2];
        #pragma unroll
        for (int k = 0; k < 2; ++k) { v2[k] = cv[k * 64 + lane]; i2[k] = ci[k * 64 + lane]; }
        for (int rd = 0; rd < 32; ++rd) {
            float best = v2[0]; int bi = i2[0]; int bk = 0;
            if (v2[1] > best || (v2[1] == best && i2[1] < bi)) { best = v2[1]; bi = i2[1]; bk = 1; }
            float rv = best; int ridx = bi;
            #pragma unroll
            for (int s = 1; s < 64; s <<= 1) {
                float ov = __shfl_xor(rv, s); int oi = __shfl_xor(ridx, s);
                if (ov > rv || (ov == rv && oi < ridx)) { rv = ov; ridx = oi; }
            }
            if (lane == 0) cand[p * NCAND + rd] = ridx;
            if (ridx == bi) v2[bk] = -1e30f;
        }
    } else if (w == 1) {
        if (lane < NCAND) ex_logit[p * NCAND + lane] = 0.f;
    }
}

// ---------- exact fp32 recompute: phase 1 (h) ----------
// grid 64p x 2ct x 8jc = 1024 blocks, 16 cands per block
__global__ __launch_bounds__(256)
void exact_h_kernel(const float* __restrict__ query,
                    const float* __restrict__ W1, const float* __restrict__ b1,
                    const int* __restrict__ cand, float* __restrict__ ex_h) {
    __shared__ float qs[DDIM][QPAD];
    __shared__ float hpart[4][16][64];
    int blk = blockIdx.x;
    int p = blk >> 4, r4 = blk & 15;
    int ct = r4 >> 3, jc = r4 & 7;
    int n = p >> 2, b = p & 3;
    int t = threadIdx.x, jj = t & 63, dg = t >> 6;
    int j = jc * 64 + jj;
    for (int c = 0; c < 16; ++c) {
        int li = cand[p * NCAND + ct * 16 + c];
        const float* qr = query + ((size_t)b * LSEQ + li) * DDIM;
        for (int d = t; d < DDIM; d += 256) qs[d][c] = qr[d];
    }
    __syncthreads();
    const float* W1n = W1 + (size_t)n * DDIM * DDIM;
    float acc[16] = {};
    for (int d = dg * 128; d < dg * 128 + 128; ++d) {
        float wvv = W1n[(size_t)d * DDIM + j];
        const float4* qv = (const float4*)&qs[d][0];
        #pragma unroll
        for (int c4 = 0; c4 < 4; ++c4) {
            float4 q4 = qv[c4];
            acc[c4 * 4 + 0] = fmaf(q4.x, wvv, acc[c4 * 4 + 0]);
            acc[c4 * 4 + 1] = fmaf(q4.y, wvv, acc[c4 * 4 + 1]);
            acc[c4 * 4 + 2] = fmaf(q4.z, wvv, acc[c4 * 4 + 2]);
            acc[c4 * 4 + 3] = fmaf(q4.w, wvv, acc[c4 * 4 + 3]);
        }
    }
    #pragma unroll
    for (int c = 0; c < 16; ++c) hpart[dg][c][jj] = acc[c];
    __syncthreads();
    const float slope = 0.01f + 0.0125f * n;
    float bias = b1[n * DDIM + j];
    for (int cc = dg; cc < 16; cc += 4) {
        float h = hpart[0][cc][jj] + hpart[1][cc][jj] + hpart[2][cc][jj]
                + hpart[3][cc][jj] + bias;
        h = h >= 0.f ? h : h * slope;
        ex_h[((size_t)p * NCAND + ct * 16 + cc) * DDIM + j] = h;
    }
}

// ---------- exact phase 2: x + exact logits ----------
__global__ __launch_bounds__(256)
void exact_x_kernel(const float* __restrict__ ex_h,
                    const float* __restrict__ W2, const float* __restrict__ b2,
                    const float* __restrict__ Wg,
                    float* __restrict__ ex_x, float* __restrict__ ex_logit) {
    __shared__ float hs[DDIM][QPAD];
    __shared__ float xpart[4][16][64];
    int blk = blockIdx.x;
    int p = blk >> 4, r4 = blk & 15;
    int ct = r4 >> 3, jc = r4 & 7;
    int n = p >> 2;
    int t = threadIdx.x, jj = t & 63, dg = t >> 6;
    int j = jc * 64 + jj;
    for (int c = 0; c < 16; ++c) {
        const float* hr = ex_h + ((size_t)p * NCAND + ct * 16 + c) * DDIM;
        for (int d = t; d < DDIM; d += 256) hs[d][c] = hr[d];
    }
    __syncthreads();
    const float* W2n = W2 + (size_t)n * DDIM * DDIM;
    float acc[16] = {};
    for (int d = dg * 128; d < dg * 128 + 128; ++d) {
        float wvv = W2n[(size_t)d * DDIM + j];
        const float4* hv = (const float4*)&hs[d][0];
        #pragma unroll
        for (int c4 = 0; c4 < 4; ++c4) {
            float4 h4 = hv[c4];
            acc[c4 * 4 + 0] = fmaf(h4.x, wvv, acc[c4 * 4 + 0]);
            acc[c4 * 4 + 1] = fmaf(h4.y, wvv, acc[c4 * 4 + 1]);
            acc[c4 * 4 + 2] = fmaf(h4.z, wvv, acc[c4 * 4 + 2]);
            acc[c4 * 4 + 3] = fmaf(h4.w, wvv, acc[c4 * 4 + 3]);
        }
    }
    #pragma unroll
    for (int c = 0; c < 16; ++c) xpart[dg][c][jj] = acc[c];
    __syncthreads();
    float bias = b2[n * DDIM + j];
    float wg = Wg[n * DDIM + j];
    for (int cc = dg; cc < 16; cc += 4) {
        float a = xpart[0][cc][jj] + xpart[1][cc][jj] + xpart[2][cc][jj]
                + xpart[3][cc][jj] + bias;
        float x = tanhf(a);
        ex_x[((size_t)p * NCAND + ct * 16 + cc) * DDIM + j] = x;
        float lp = x * wg;
        #pragma unroll
        for (int s = 1; s < 64; s <<= 1) lp += __shfl_xor(lp, s);
        if (jj == 0) atomicAdd(&ex_logit[p * NCAND + ct * 16 + cc], lp);
    }
}

// ---------- final: exact top-8 of 32, weight, combine, normalize ----------
__global__ __launch_bounds__(64)
void final_kernel(const float* __restrict__ ex_x, const float* __restrict__ ex_logit,
                  const int* __restrict__ cand, float* __restrict__ out)
{
    __shared__ float w8s[KTOP];
    __shared__ int   s8s[KTOP];
    int p = blockIdx.x, n = p >> 2, b = p & 3;
    int t = threadIdx.x;
    float myv = (t < NCAND) ? ex_logit[p * NCAND + t] : -1e30f;
    int myidx = (t < NCAND) ? cand[p * NCAND + t] : 0x7fffffff;
    float lmax = 0.f;
    for (int k = 0; k < KTOP; ++k) {
        float rv = myv; int ridx = myidx; int rl = t;
        #pragma unroll
        for (int s = 1; s < 64; s <<= 1) {
            float ov = __shfl_xor(rv, s); int oi = __shfl_xor(ridx, s); int ol = __shfl_xor(rl, s);
            if (ov > rv || (ov == rv && oi < ridx)) { rv = ov; ridx = oi; rl = ol; }
        }
        if (k == 0) lmax = rv;
        if (t == 0) { w8s[k] = __expf(rv - lmax); s8s[k] = rl; }
        if (t == rl) myv = -1e30f;
    }
    __syncthreads();
    float cvv[8];
    float sq = 0.f;
    int idx = 0;
    for (int d = t; d < DDIM; d += 64, ++idx) {
        float s = 0.f;
        #pragma unroll
        for (int k = 0; k < KTOP; ++k)
            s = fmaf(w8s[k], ex_x[((size_t)p * NCAND + s8s[k]) * DDIM + d], s);
        cvv[idx] = s;
        sq += s * s;
    }
    #pragma unroll
    for (int s = 1; s < 64; s <<= 1) sq += __shfl_xor(sq, s);
    float norm = fmaxf(sqrtf(sq), 1e-12f);
    idx = 0;
    for (int d = t; d < DDIM; d += 64, ++idx)
        out[((size_t)b * NMEM + n) * DDIM + d] = cvv[idx] / norm;
}

extern "C" void kernel_launch(void* const* d_in, const int* in_sizes, int n_in,
                              void* d_out, int out_size, void* d_ws, size_t ws_size,
                              hipStream_t stream)
{
    const float* query = (const float*)d_in[0];
    const float* W1    = (const float*)d_in[1];
    const float* b1    = (const float*)d_in[2];
    const float* W2    = (const float*)d_in[3];
    const float* b2    = (const float*)d_in[4];
    const float* Wg    = (const float*)d_in[5];
    // d_in[6] = bg cancels under softmax+normalize; d_in[7] = topk (hardcoded 8)

    char* ws = (char*)d_ws;
    const size_t MB = 1024 * 1024;
    unsigned char* Q8   = (unsigned char*)(ws);                  // 8 MB
    unsigned char* W1T8 = (unsigned char*)(ws + 8 * MB);         // 4 MB
    unsigned char* W2T8 = (unsigned char*)(ws + 12 * MB);        // 4 MB
    float* logits   = (float*)(ws + 16 * MB);                    // 1 MB
    int*   cand     = (int*)  (ws + 17 * MB);                    // 8 KB
    float* ex_logit = (float*)(ws + 17 * MB + 16384);            // 8 KB
    float* ex_h     = (float*)(ws + 20 * MB);                    // 4 MB
    float* ex_x     = (float*)(ws + 28 * MB);                    // 4 MB

    prep_kernel<<<4096, 256, 0, stream>>>(query, W1, W2, Q8, W1T8, W2T8);
    fused_mlp_kernel<<<4096, 256, 0, stream>>>(Q8, W1T8, W2T8, b1, b2, Wg, logits);
    topcand_kernel<<<64, 256, 0, stream>>>(logits, cand, ex_logit);
    exact_h_kernel<<<1024, 256, 0, stream>>>(query, W1, b1, cand, ex_h);
    exact_x_kernel<<<1024, 256, 0, stream>>>(ex_h, W2, b2, Wg, ex_x, ex_logit);
    final_kernel<<<64, 64, 0, stream>>>(ex_x, ex_logit, cand, (float*)d_out);
}